// Round 6
// baseline (1419.287 us; speedup 1.0000x reference)
//
#include <hip/hip_runtime.h>
#include <hip/hip_bf16.h>

#define NN 50000
#define RR 8
#define EE 200000
#define EDD 400000
#define SCB 196   // ceil(NN/256) scan blocks
#define CH 5000   // phase-a node chunk (10 chunks)
#define CHK 16    // histogram privatization chunks
#define FR 8      // fillw dst ranges
#define FRN 6250  // nodes per range

typedef __attribute__((ext_vector_type(8))) short short8;
typedef __attribute__((ext_vector_type(4))) float floatx4;

static __device__ __forceinline__ unsigned short f2bf(float f) {
    union { float f; unsigned u; } v; v.f = f;
    unsigned r = v.u + 0x7fff + ((v.u >> 16) & 1);
    return (unsigned short)(r >> 16);
}
static __device__ __forceinline__ float bf2f(unsigned short h) {
    union { unsigned u; float f; } v; v.u = ((unsigned)h) << 16;
    return v.f;
}
// async global->LDS, 16B per lane; LDS dest = uniform base + lane*16
static __device__ __forceinline__ void gload_lds16(const unsigned short* g, unsigned short* l) {
    __builtin_amdgcn_global_load_lds(
        (const __attribute__((address_space(1))) void*)g,
        (__attribute__((address_space(3))) void*)l,
        16, 0, 0);
}

// ---------------- privatized degree histogram: 8-bit LDS bins, non-atomic flush ----------------
__global__ __launch_bounds__(256) void k_histp(const int* __restrict__ src, const int* __restrict__ dst,
                                               unsigned char* __restrict__ tmp) {
    __shared__ unsigned lh[12512];   // 50048 bytes, 8-bit bins
    int chunk = blockIdx.x, r = blockIdx.y, which = blockIdx.z;
    const int* idx = (which ? dst : src) + (size_t)r * EE;
    for (int i = threadIdx.x; i < 12512; i += 256) lh[i] = 0;
    __syncthreads();
    int e0 = chunk * (EE / CHK);
    for (int e = e0 + threadIdx.x; e < e0 + EE / CHK; e += 256) {
        int n = idx[e];
        atomicAdd(&lh[n >> 2], 1u << ((n & 3) * 8));
    }
    __syncthreads();
    unsigned* t = (unsigned*)(tmp + (((size_t)(which * RR + r) * CHK + chunk) * 50048));
    for (int i = threadIdx.x; i < 12512; i += 256) t[i] = lh[i];
}

// ---------------- reduce the CHK private copies -> int degree arrays ----------------
__global__ void k_reduce(const unsigned char* __restrict__ tmp,
                         int* __restrict__ outdeg, int* __restrict__ indeg) {
    int i = blockIdx.x * 256 + threadIdx.x;
    if (i >= 2 * RR * 12512) return;
    int wr = i / 12512;        // which*RR + r
    int wd = i - wr * 12512;   // word index (4 nodes)
    unsigned s0 = 0, s1 = 0, s2 = 0, s3 = 0;
    const unsigned* base = (const unsigned*)(tmp + (size_t)wr * CHK * 50048) + wd;
    #pragma unroll
    for (int c = 0; c < CHK; c++) {
        unsigned v = base[(size_t)c * 12512];
        s0 += v & 255u; s1 += (v >> 8) & 255u; s2 += (v >> 16) & 255u; s3 += (v >> 24) & 255u;
    }
    int which = wr / RR, r = wr - which * RR;
    int n = wd * 4;
    int* deg = (which ? indeg : outdeg) + (size_t)r * NN;
    if (n < NN) {
        deg[n] = (int)s0;
        if (n + 1 < NN) deg[n + 1] = (int)s1;
        if (n + 2 < NN) deg[n + 2] = (int)s2;
        if (n + 3 < NN) deg[n + 3] = (int)s3;
    }
}

// ---------------- norms: in-place int degree -> float rsqrt ----------------
__global__ void k_norms(int* __restrict__ outdeg, int* __restrict__ indeg) {
    int i = blockIdx.x * blockDim.x + threadIdx.x;
    if (i >= RR * NN) return;
    int od = outdeg[i];
    int id = indeg[i];
    ((float*)outdeg)[i] = od > 0 ? rsqrtf((float)od) : 0.f;
    ((float*)indeg)[i]  = id > 0 ? rsqrtf((float)id) : 0.f;
}

// ---------------- parallel scan: phase A (per-block sums) ----------------
__global__ void k_scanA(const int* __restrict__ indeg, int* __restrict__ bsum) {
    int r = blockIdx.y;
    int i = blockIdx.x * 256 + threadIdx.x;
    int v = (i < NN) ? indeg[(size_t)r * NN + i] : 0;
    #pragma unroll
    for (int d = 32; d > 0; d >>= 1) v += __shfl_down(v, d, 64);
    __shared__ int ws4[4];
    if ((threadIdx.x & 63) == 0) ws4[threadIdx.x >> 6] = v;
    __syncthreads();
    if (threadIdx.x == 0) bsum[r * SCB + blockIdx.x] = ws4[0] + ws4[1] + ws4[2] + ws4[3];
}

// ---------------- phase B: exclusive scan of SCB block sums per relation ----------------
__global__ void k_scanB(int* __restrict__ bsum, int* __restrict__ offs) {
    int r = blockIdx.x;
    int t = threadIdx.x;
    int v = (t < SCB) ? bsum[r * SCB + t] : 0;
    int lane = t & 63, wid = t >> 6;
    int sv = v;
    #pragma unroll
    for (int d = 1; d < 64; d <<= 1) {
        int u = __shfl_up(sv, d, 64);
        if (lane >= d) sv += u;
    }
    __shared__ int wsum[4];
    if (lane == 63) wsum[wid] = sv;
    __syncthreads();
    int add = 0;
    for (int x = 0; x < wid; x++) add += wsum[x];
    int incl = sv + add;
    if (t < SCB) bsum[r * SCB + t] = incl - v;
    if (t == 255) offs[(size_t)r * (NN + 1) + NN] = incl;  // grand total
}

// ---------------- phase C: intra-block exclusive scan + base ----------------
__global__ void k_scanC(const int* __restrict__ indeg, const int* __restrict__ bsum,
                        int* __restrict__ offs) {
    int r = blockIdx.y;
    int i = blockIdx.x * 256 + threadIdx.x;
    int v = (i < NN) ? indeg[(size_t)r * NN + i] : 0;
    int lane = threadIdx.x & 63, wid = threadIdx.x >> 6;
    int sv = v;
    #pragma unroll
    for (int d = 1; d < 64; d <<= 1) {
        int u = __shfl_up(sv, d, 64);
        if (lane >= d) sv += u;
    }
    __shared__ int wsum[4];
    if (lane == 63) wsum[wid] = sv;
    __syncthreads();
    int add = bsum[r * SCB + blockIdx.x];
    for (int x = 0; x < wid; x++) add += wsum[x];
    if (i < NN) offs[(size_t)r * (NN + 1) + i] = sv - v + add;
}

// ---------------- CSR fill v2: dst-range partitioned, single-writer-per-line ----------------
// grid (FR, RR). Block streams relation r's full edge list (int4), keeps dst in its 6250-node
// range, position from LDS cursor. All writes to a csrw line come from ONE block -> L2
// assembles full lines -> writeback ~13 MB instead of 101 MB (r5 counter: 64B/record).
__global__ __launch_bounds__(256) void k_fillw2(const int* __restrict__ src, const int* __restrict__ dst,
                                                const int* __restrict__ offs, const float* __restrict__ ns,
                                                int2* __restrict__ csrw) {
    __shared__ int cur[FRN];   // 25 KB
    int range = blockIdx.x, r = blockIdx.y;
    int lo = range * FRN;
    for (int i = threadIdx.x; i < FRN; i += 256) cur[i] = 0;
    __syncthreads();
    const int4* sp = (const int4*)(src + (size_t)r * EE);
    const int4* dp = (const int4*)(dst + (size_t)r * EE);
    const int* offr = offs + r * (NN + 1);
    const float* nsr = ns + (size_t)r * NN;
    int2* cw = csrw + (size_t)r * EE;
    for (int e4 = threadIdx.x; e4 < EE / 4; e4 += 256) {
        int4 d4 = dp[e4];
        int4 s4 = sp[e4];
        #pragma unroll
        for (int u = 0; u < 4; u++) {
            int d = (u == 0 ? d4.x : u == 1 ? d4.y : u == 2 ? d4.z : d4.w) - lo;
            if ((unsigned)d < (unsigned)FRN) {
                int s = (u == 0 ? s4.x : u == 1 ? s4.y : u == 2 ? s4.z : s4.w);
                int pos = offr[lo + d] + atomicAdd(&cur[d], 1);
                int2 v;
                v.x = s;
                v.y = __float_as_int(nsr[s]);
                cw[pos] = v;
            }
        }
    }
}

// ---------------- decoder prep (Mcat, cvec) + bias sums, one launch ----------------
__global__ void k_prep(const float* __restrict__ Wp1, const float* __restrict__ Wp2,
                       const float* __restrict__ bp1, const float* __restrict__ bp2,
                       const float* __restrict__ b2a, const float* __restrict__ b2b,
                       const float* __restrict__ b3a, const float* __restrict__ b3b,
                       float* __restrict__ Mcat, float* __restrict__ cvec,
                       float* __restrict__ bs) {
    int bx = blockIdx.x;
    if (bx < 16) {
        int t = bx * 256 + threadIdx.x;      // 4096 elements
        int i = t >> 4, j = t & 15;
        int half = j >> 3, jj = j & 7;
        const float* wrow = Wp1 + (size_t)(half * 256 + i) * 256;
        float s = 0.f;
        for (int k = 0; k < 256; k++) s += wrow[k] * Wp2[k * 8 + jj];
        Mcat[i * 16 + j] = s;
    } else if (bx == 16) {
        int j = threadIdx.x;
        if (j < 8) {
            float s = bp2[j];
            for (int k = 0; k < 256; k++) s += bp1[k] * Wp2[k * 8 + j];
            cvec[j] = s;
        }
    } else {
        int j = threadIdx.x;  // 256
        float s = 0.f;
        for (int r = 0; r < RR; r++) s += b2a[r * 256 + j];
        bs[j] = s;
        if (j < 128) {
            s = 0.f;
            for (int r = 0; r < RR; r++) s += b2b[r * 128 + j];
            bs[256 + j] = s;
        }
        s = 0.f;
        for (int r = 0; r < RR; r++) s += b3a[r * 256 + j];
        bs[512 + j] = s;
        if (j < 128) {
            s = 0.f;
            for (int r = 0; r < RR; r++) s += b3b[r * 128 + j];
            bs[768 + j] = s;
        }
    }
}

// ---------------- fold b-layer weights through decoder: FmatT[128][512] bf16, cfold[16] ----
__global__ void k_fold(const float* __restrict__ W2b, const float* __restrict__ W3b,
                       const float* __restrict__ Mcat, const float* __restrict__ bs,
                       unsigned short* __restrict__ FmatT, float* __restrict__ cfold) {
    int bx = blockIdx.x;
    if (bx < 256) {
        int idx = bx * 256 + threadIdx.x;      // 65536 = 128 rows x 512 cols
        int rj = idx >> 9, i = idx & 511;
        int r = rj >> 4, j = rj & 15;
        float s = 0.f;
        if (i < 256) {
            const float* wr = W2b + ((size_t)r * 256 + i) * 128;
            for (int c = 0; c < 128; c++) s += wr[c] * Mcat[c * 16 + j];
        } else {
            const float* wr = W3b + ((size_t)r * 256 + (i - 256)) * 128;
            for (int c = 0; c < 128; c++) s += wr[c] * Mcat[(128 + c) * 16 + j];
        }
        FmatT[(size_t)rj * 512 + i] = f2bf(s);
    } else {
        int j = threadIdx.x;
        if (j < 16) {
            float s = 0.f;
            for (int c = 0; c < 128; c++)
                s += bs[256 + c] * Mcat[c * 16 + j] + bs[768 + c] * Mcat[(128 + c) * 16 + j];
            cfold[j] = s;
        }
    }
}

// ---------------- interleaved bf16 cast: XH[m] = [x2(256) | x3(300) | 0 x4], stride 560 ----
__global__ void k_castx(const float* __restrict__ x2, const float* __restrict__ x3,
                        unsigned short* __restrict__ XH) {
    int i = blockIdx.x * 256 + threadIdx.x;
    if (i >= NN * 560) return;
    int row = i / 560, col = i - row * 560;
    float v;
    if (col < 256) v = x2[(size_t)row * 256 + col];
    else if (col < 556) v = x3[(size_t)row * 300 + (col - 256)];
    else v = 0.f;
    XH[i] = f2bf(v);
}

// ---------------- weight transposes (a-layers only): WT[n][r][kpad] bf16 ----------------
__global__ void k_wt2(const float* __restrict__ W2a, const float* __restrict__ W3a,
                      unsigned short* __restrict__ WT2, unsigned short* __restrict__ WT3) {
    const float* W; unsigned short* WT; int K0, Kpad;
    if (blockIdx.y == 0) { W = W2a; WT = WT2; K0 = 256; Kpad = 256; }
    else                 { W = W3a; WT = WT3; K0 = 300; Kpad = 304; }
    int i = blockIdx.x * 256 + threadIdx.x;
    int total = 256 * RR * Kpad;
    if (i >= total) return;
    int n = i / (RR * Kpad);
    int rem = i - n * (RR * Kpad);
    int r = rem / Kpad;
    int k = rem - r * Kpad;
    float v = (k < K0) ? W[((size_t)r * K0 + k) * 256 + n] : 0.f;
    WT[i] = f2bf(v);
}

// ---------------- dual-payload aggregation v4: whole-wave row loads ----------------
// Wave per (node, r). Lane l owns cols [8l, 8l+8) of the 560-col row: one 64-lane short8
// load covers bytes [0,1024), a 6-lane tail covers [1024,1120). 2 VMEM instrs/edge (was 3),
// no cross-half reduction, fewer accumulator VGPRs. Records shfl-broadcast from one
// coalesced block load; wave-uniform break avoids clamped redundant loads.
__global__ __launch_bounds__(256) void k_aggp(
        const unsigned short* __restrict__ xb,
        const int2* __restrict__ csrw, const int* __restrict__ offs,
        const float* __restrict__ nd, int nbase,
        unsigned short* __restrict__ Y2, unsigned short* __restrict__ Y3) {
    int lane = threadIdx.x & 63;
    int sub = threadIdx.x >> 6;
    int bn = blockIdx.x * 4 + sub;
    int n = nbase + bn;
    int r = blockIdx.y;
    int o0 = offs[r * (NN + 1) + n];
    int o1 = offs[r * (NN + 1) + n + 1];
    o0 = __builtin_amdgcn_readfirstlane(o0);
    o1 = __builtin_amdgcn_readfirstlane(o1);
    int cnt = o1 - o0;
    float ndv = nd[(size_t)r * NN + n];
    const int2* cs = csrw + (size_t)r * EE + o0;
    bool tl = lane < 6;          // tail cols 512..559
    float va[8], vc[8];
    #pragma unroll
    for (int q = 0; q < 8; q++) { va[q] = 0.f; vc[q] = 0.f; }

    for (int eb = 0; eb < cnt; eb += 64) {
        int rem = cnt - eb;                        // > 0
        int2 rec = cs[eb + min(lane, rem - 1)];    // coalesced record block
        int kmax = rem < 64 ? rem : 64;
        for (int kb = 0; kb < kmax; kb += 4) {
            #pragma unroll
            for (int u = 0; u < 4; u++) {
                int k = kb + u;
                if (k >= kmax) break;              // wave-uniform
                int sidx = __shfl(rec.x, k, 64);
                float f = __int_as_float(__shfl(rec.y, k, 64));
                const unsigned short* p = xb + (size_t)(unsigned)sidx * 560;
                short8 M = *(const short8*)(p + lane * 8);
                #pragma unroll
                for (int q = 0; q < 8; q++) va[q] += f * bf2f((unsigned short)M[q]);
                if (tl) {
                    short8 C = *(const short8*)(p + 512 + lane * 8);
                    #pragma unroll
                    for (int q = 0; q < 8; q++) vc[q] += f * bf2f((unsigned short)C[q]);
                }
            }
        }
    }
    short8 o;
    #pragma unroll
    for (int q = 0; q < 8; q++) o[q] = (short)f2bf(va[q] * ndv);
    if (lane < 32) {
        *(short8*)(Y2 + (size_t)bn * 2048 + r * 256 + lane * 8) = o;
    } else {
        *(short8*)(Y3 + (size_t)bn * 2432 + r * 304 + (lane - 32) * 8) = o;
    }
    if (tl) {
        short8 oc;
        #pragma unroll
        for (int q = 0; q < 8; q++) oc[q] = (short)f2bf(vc[q] * ndv);
        *(short8*)(Y3 + (size_t)bn * 2432 + r * 304 + 256 + lane * 8) = oc;
    }
}

// ---------------- generic bf16 MFMA GEMM (r0-proven), used for G projection ----------------
// flags: 1=addbias, 2=accum(read Cin fp32), 4=relu, 8=out bf16 (else fp32)
template<int TN>
__global__ __launch_bounds__(256) void k_gemm_bf(
        const unsigned short* __restrict__ A, int lda,
        const unsigned short* __restrict__ BT, int ldb,
        const float* __restrict__ bias,
        const float* __restrict__ Cin, int ldcin,
        void* __restrict__ Cout, int ldc,
        int M, int K, int flags) {
    constexpr int BN = TN * 32;
    __shared__ unsigned short As[128 * 64];
    __shared__ unsigned short Bs[BN * 64];
    int m0 = blockIdx.x * 128;
    int n0 = blockIdx.y * BN;
    int t = threadIdx.x;
    int w = t >> 6, l = t & 63;
    int qm = (w >> 1) * 64, qn = (w & 1) * (TN * 16);
    int lr = l & 15, lg = l >> 4;
    int lrow = l >> 3;
    int lch  = (l & 7) ^ lrow;

    floatx4 acc[4][TN];
    #pragma unroll
    for (int a = 0; a < 4; a++)
        #pragma unroll
        for (int b = 0; b < TN; b++)
            acc[a][b] = (floatx4){0.f, 0.f, 0.f, 0.f};

    for (int k0 = 0; k0 < K; k0 += 64) {
        #pragma unroll
        for (int j = 0; j < 4; j++) {
            int seg = w * 4 + j;
            int gr = m0 + seg * 8 + lrow; if (gr > M - 1) gr = M - 1;
            gload_lds16(A + (size_t)gr * lda + k0 + lch * 8, &As[seg * 512]);
        }
        #pragma unroll
        for (int j = 0; j < TN; j++) {
            int seg = w * TN + j;
            int row = n0 + seg * 8 + lrow;
            gload_lds16(BT + (size_t)row * ldb + k0 + lch * 8, &Bs[seg * 512]);
        }
        __syncthreads();
        #pragma unroll
        for (int ks = 0; ks < 2; ks++) {
            int slot = ((ks * 4 + lg) ^ (lr & 7)) * 8;
            short8 af[4], bf[TN];
            #pragma unroll
            for (int i = 0; i < 4; i++)
                af[i] = *(const short8*)&As[(qm + i * 16 + lr) * 64 + slot];
            #pragma unroll
            for (int i = 0; i < TN; i++)
                bf[i] = *(const short8*)&Bs[(qn + i * 16 + lr) * 64 + slot];
            #pragma unroll
            for (int tm = 0; tm < 4; tm++)
                #pragma unroll
                for (int tn = 0; tn < TN; tn++)
                    acc[tm][tn] = __builtin_amdgcn_mfma_f32_16x16x32_bf16(
                        af[tm], bf[tn], acc[tm][tn], 0, 0, 0);
        }
        __syncthreads();
    }

    int addbias = flags & 1, accum = flags & 2, relu = flags & 4, outbf = flags & 8;
    #pragma unroll
    for (int tm = 0; tm < 4; tm++) {
        int rbase = m0 + qm + tm * 16 + lg * 4;
        #pragma unroll
        for (int reg = 0; reg < 4; reg++) {
            int row = rbase + reg;
            if (row >= M) continue;
            #pragma unroll
            for (int tn = 0; tn < TN; tn++) {
                int col = n0 + qn + tn * 16 + lr;
                float v = acc[tm][tn][reg];
                if (addbias) v += bias[col];
                if (accum) v += Cin[(size_t)row * ldcin + col];
                if (relu) v = fmaxf(v, 0.f);
                if (outbf) ((unsigned short*)Cout)[(size_t)row * ldc + col] = f2bf(v);
                else       ((float*)Cout)[(size_t)row * ldc + col] = v;
            }
        }
    }
}

// ---------------- paired a-layer GEMM, BM=64/BN=64 (632 blocks -> no tail quantization) ------
// z=0 -> 2a (K=2048), z=1 -> 3a (K=2432); out hb[(nbase+row)*512 + z*256 + col] relu bf16
__global__ __launch_bounds__(256) void k_gemm2(
        const unsigned short* __restrict__ Y2, const unsigned short* __restrict__ Y3,
        const unsigned short* __restrict__ WT2, const unsigned short* __restrict__ WT3,
        const float* __restrict__ bs, unsigned short* __restrict__ hb,
        int nbase, int M) {
    __shared__ unsigned short As[64 * 64];
    __shared__ unsigned short Bs[64 * 64];
    int z = blockIdx.z;
    const unsigned short* A  = z ? Y3 : Y2;
    const unsigned short* BT = z ? WT3 : WT2;
    int lda = z ? 2432 : 2048;
    int K = lda;
    const float* bias = bs + z * 512;
    int m0 = blockIdx.x * 64;
    int n0 = blockIdx.y * 64;
    int t = threadIdx.x;
    int w = t >> 6, l = t & 63;
    int qm = (w >> 1) * 32, qn = (w & 1) * 32;
    int lr = l & 15, lg = l >> 4;
    int lrow = l >> 3;
    int lch  = (l & 7) ^ lrow;

    floatx4 acc[2][2];
    #pragma unroll
    for (int a = 0; a < 2; a++)
        #pragma unroll
        for (int b = 0; b < 2; b++)
            acc[a][b] = (floatx4){0.f, 0.f, 0.f, 0.f};

    for (int k0 = 0; k0 < K; k0 += 64) {
        #pragma unroll
        for (int j = 0; j < 2; j++) {
            int seg = w * 2 + j;                   // 8 segs x 8 rows = 64 rows
            int gr = m0 + seg * 8 + lrow; if (gr > M - 1) gr = M - 1;
            gload_lds16(A + (size_t)gr * lda + k0 + lch * 8, &As[seg * 512]);
        }
        #pragma unroll
        for (int j = 0; j < 2; j++) {
            int seg = w * 2 + j;
            int row = n0 + seg * 8 + lrow;         // <= 255, WT has 256 rows
            gload_lds16(BT + (size_t)row * lda + k0 + lch * 8, &Bs[seg * 512]);
        }
        __syncthreads();
        #pragma unroll
        for (int ks = 0; ks < 2; ks++) {
            int slot = ((ks * 4 + lg) ^ (lr & 7)) * 8;
            short8 af[2], bf[2];
            #pragma unroll
            for (int i = 0; i < 2; i++)
                af[i] = *(const short8*)&As[(qm + i * 16 + lr) * 64 + slot];
            #pragma unroll
            for (int i = 0; i < 2; i++)
                bf[i] = *(const short8*)&Bs[(qn + i * 16 + lr) * 64 + slot];
            #pragma unroll
            for (int tm = 0; tm < 2; tm++)
                #pragma unroll
                for (int tn = 0; tn < 2; tn++)
                    acc[tm][tn] = __builtin_amdgcn_mfma_f32_16x16x32_bf16(
                        af[tm], bf[tn], acc[tm][tn], 0, 0, 0);
        }
        __syncthreads();
    }

    #pragma unroll
    for (int tm = 0; tm < 2; tm++) {
        int rbase = m0 + qm + tm * 16 + lg * 4;
        #pragma unroll
        for (int reg = 0; reg < 4; reg++) {
            int row = rbase + reg;
            if (row >= M) continue;
            #pragma unroll
            for (int tn = 0; tn < 2; tn++) {
                int col = n0 + qn + tn * 16 + lr;
                float v = fmaxf(acc[tm][tn][reg] + bias[col], 0.f);
                hb[(size_t)(nbase + row) * 512 + z * 256 + col] = f2bf(v);
            }
        }
    }
}

// ---------------- 16-dim projected aggregation v2: slot = relation pairs, rec-broadcast ------
// AB[n,j] = cfold[j] + [j<8]cvec[j] + sum_r nd_r[n] * sum_e ns_e * G[src_e*128 + r*16 + j]
__global__ __launch_bounds__(256) void k_aggAB(
        const int2* __restrict__ csrw, const int* __restrict__ offs,
        const float* __restrict__ nd, const float* __restrict__ G,
        const float* __restrict__ cfold, const float* __restrict__ cvec,
        float* __restrict__ AB) {
    int lane = threadIdx.x & 63, sub = threadIdx.x >> 6;
    int n = blockIdx.x * 4 + sub;
    int slot = lane >> 4, j = lane & 15;
    int jb = slot << 4;                     // group base lane for shfl
    float acc = 0.f;
    for (int hh = 0; hh < 2; hh++) {
        int r = slot + hh * 4;
        int o0 = offs[r * (NN + 1) + n];
        int o1 = offs[r * (NN + 1) + n + 1];
        float ndv = nd[(size_t)r * NN + n];
        const int2* cs = csrw + (size_t)r * EE + o0;
        int cnt = o1 - o0;
        float t0 = 0.f, t1 = 0.f;
        for (int eb = 0; eb < cnt; eb += 16) {
            int rem = cnt - eb;
            int2 rec = cs[eb + min(j, rem - 1)];   // 16 records per slot, coalesced
            int kmax = rem < 16 ? rem : 16;
            for (int k = 0; k < kmax; k += 2) {
                int s0 = __shfl(rec.x, jb + k, 64);
                float f0 = __int_as_float(__shfl(rec.y, jb + k, 64));
                int k1 = k + 1 < kmax ? k + 1 : kmax - 1;
                int s1 = __shfl(rec.x, jb + k1, 64);
                float f1 = (k + 1 < kmax) ? __int_as_float(__shfl(rec.y, jb + k1, 64)) : 0.f;
                t0 += f0 * G[(size_t)(unsigned)s0 * 128 + r * 16 + j];
                t1 += f1 * G[(size_t)(unsigned)s1 * 128 + r * 16 + j];
            }
        }
        acc += ndv * (t0 + t1);
    }
    acc += __shfl_xor(acc, 16, 64);
    acc += __shfl_xor(acc, 32, 64);
    if (lane < 16) AB[(size_t)n * 16 + j] = acc + cfold[j] + (j < 8 ? cvec[j] : 0.f);
}

// ---------------- per-edge decoder (float4, cvec pre-folded) ----------------
__global__ void k_dec(const int* __restrict__ dsrc, const int* __restrict__ ddst,
                      const float* __restrict__ AB, float* __restrict__ out) {
    int e = blockIdx.x * 256 + threadIdx.x;
    if (e >= EDD) return;
    int s = dsrc[e], d = ddst[e];
    const float4* as = (const float4*)(AB + (size_t)s * 16);
    const float4* ad = (const float4*)(AB + (size_t)d * 16 + 8);
    float4 x0 = as[0], x1 = as[1], y0 = ad[0], y1 = ad[1];
    float4 o0 = {x0.x + y0.x, x0.y + y0.y, x0.z + y0.z, x0.w + y0.w};
    float4 o1 = {x1.x + y1.x, x1.y + y1.y, x1.z + y1.z, x1.w + y1.w};
    float4* op = (float4*)(out + (size_t)e * 8);
    op[0] = o0; op[1] = o1;
}

extern "C" void kernel_launch(void* const* d_in, const int* in_sizes, int n_in,
                              void* d_out, int out_size, void* d_ws, size_t ws_size,
                              hipStream_t stream) {
    const float* x2  = (const float*)d_in[0];
    const float* x3  = (const float*)d_in[1];
    const int*   src = (const int*)d_in[2];
    const int*   dst = (const int*)d_in[3];
    const int*   dsrc = (const int*)d_in[4];
    const int*   ddst = (const int*)d_in[5];
    const float* W2a = (const float*)d_in[6];
    const float* b2a = (const float*)d_in[7];
    const float* W2b = (const float*)d_in[8];
    const float* b2b = (const float*)d_in[9];
    const float* W3a = (const float*)d_in[10];
    const float* b3a = (const float*)d_in[11];
    const float* W3b = (const float*)d_in[12];
    const float* b3b = (const float*)d_in[13];
    const float* Wp1 = (const float*)d_in[14];
    const float* bp1 = (const float*)d_in[15];
    const float* Wp2 = (const float*)d_in[16];
    const float* bp2 = (const float*)d_in[17];
    float* out = (float*)d_out;

    // ---- workspace layout (~172 MB < proven 182.4 MB bound) ----
    char* ws = (char*)d_ws;
    size_t off = 0;
    auto alloc = [&](size_t nbytes) {
        char* p = ws + off;
        off += nbytes;
        off = (off + 255) & ~(size_t)255;
        return p;
    };
    float* ns   = (float*)alloc((size_t)RR * NN * 4);        // aliases outdeg
    float* nd   = (float*)alloc((size_t)RR * NN * 4);        // aliases indeg
    int*   offs = (int*)alloc((size_t)RR * (NN + 1) * 4);
    int2*  csrw = (int2*)alloc((size_t)RR * EE * 8);
    unsigned short* XH     = (unsigned short*)alloc((size_t)NN * 560 * 2);  // [x2|x3|pad] interleaved
    unsigned short* hbuf23 = (unsigned short*)alloc((size_t)NN * 512 * 2);  // [h2a|h3a] interleaved
    unsigned short* WT2a   = (unsigned short*)alloc((size_t)256 * 2048 * 2);
    unsigned short* WT3a   = (unsigned short*)alloc((size_t)256 * 2432 * 2);
    unsigned short* FmatT  = (unsigned short*)alloc((size_t)128 * 512 * 2);
    char* YR = alloc((size_t)CH * (2048 + 2432) * 2);        // Y2a|Y3a; also htmp/G/AB
    float* Mcat  = (float*)alloc(4096 * 4);
    float* cvec  = (float*)alloc(64 * 4);
    float* bsums = (float*)alloc(1024 * 4);
    float* cfold = (float*)alloc(64 * 4);
    int*   bsum  = (int*)alloc((size_t)RR * SCB * 4);

    unsigned short* Y2a = (unsigned short*)YR;
    unsigned short* Y3a = Y2a + (size_t)CH * 2048;
    int*   outdeg = (int*)ns;
    int*   indeg  = (int*)nd;
    unsigned char* htmp = (unsigned char*)YR;              // 12.8 MB, live during histp/reduce
    float* G      = (float*)YR;                            // [NN x 128] f32, live after phase a
    float* AB     = (float*)(YR + (size_t)NN * 128 * 4);   // 3.2 MB after G

    // ---- graph prep ----
    k_histp<<<dim3(CHK, RR, 2), 256, 0, stream>>>(src, dst, htmp);
    k_reduce<<<(2 * RR * 12512 + 255) / 256, 256, 0, stream>>>(htmp, outdeg, indeg);
    k_scanA<<<dim3(SCB, RR), 256, 0, stream>>>(indeg, bsum);
    k_scanB<<<RR, 256, 0, stream>>>(bsum, offs);
    k_scanC<<<dim3(SCB, RR), 256, 0, stream>>>(indeg, bsum, offs);
    k_norms<<<(RR * NN + 255) / 256, 256, 0, stream>>>(outdeg, indeg);
    k_fillw2<<<dim3(FR, RR), 256, 0, stream>>>(src, dst, offs, ns, csrw);
    k_prep<<<18, 256, 0, stream>>>(Wp1, Wp2, bp1, bp2, b2a, b2b, b3a, b3b, Mcat, cvec, bsums);
    k_fold<<<257, 256, 0, stream>>>(W2b, W3b, Mcat, bsums, FmatT, cfold);

    k_castx<<<(NN * 560 + 255) / 256, 256, 0, stream>>>(x2, x3, XH);
    k_wt2<<<dim3((256 * RR * 304 + 255) / 256, 2), 256, 0, stream>>>(W2a, W3a, WT2a, WT3a);

    // ---- phase a: chunked dual aggregation + paired GEMM -> hbuf23 (relu bf16) ----
    for (int c = 0; c < NN / CH; c++) {
        k_aggp<<<dim3(CH / 4, RR), 256, 0, stream>>>(XH, csrw, offs, nd, c * CH, Y2a, Y3a);
        k_gemm2<<<dim3((CH + 63) / 64, 4, 2), 256, 0, stream>>>(
            Y2a, Y3a, WT2a, WT3a, bsums, hbuf23, c * CH, CH);
    }

    // ---- phase b (folded): G = hbuf23 @ FmatT^T  [NN x 128] f32 ----
    k_gemm_bf<1><<<dim3((NN + 127) / 128, 4), 256, 0, stream>>>(
        hbuf23, 512, FmatT, 512, bsums, (const float*)nullptr, 0,
        (void*)G, 128, NN, 512, 0);

    // ---- projected aggregation -> AB, then decoder ----
    k_aggAB<<<NN / 4, 256, 0, stream>>>(csrw, offs, nd, G, cfold, cvec, AB);
    k_dec<<<(EDD + 255) / 256, 256, 0, stream>>>(dsrc, ddst, AB, out);
}

// Round 7
// 1053.835 us; speedup vs baseline: 1.3468x; 1.3468x over previous
//
#include <hip/hip_runtime.h>
#include <hip/hip_bf16.h>

#define NN 50000
#define RR 8
#define EE 200000
#define EDD 400000
#define SCB 196   // ceil(NN/256) scan blocks
#define CH 5000   // phase-a node chunk (10 chunks)
#define CHK 16    // histogram privatization chunks

typedef __attribute__((ext_vector_type(8))) short short8;
typedef __attribute__((ext_vector_type(4))) float floatx4;

static __device__ __forceinline__ unsigned short f2bf(float f) {
    union { float f; unsigned u; } v; v.f = f;
    unsigned r = v.u + 0x7fff + ((v.u >> 16) & 1);
    return (unsigned short)(r >> 16);
}
static __device__ __forceinline__ float bf2f(unsigned short h) {
    union { unsigned u; float f; } v; v.u = ((unsigned)h) << 16;
    return v.f;
}
// async global->LDS, 16B per lane; LDS dest = uniform base + lane*16
static __device__ __forceinline__ void gload_lds16(const unsigned short* g, unsigned short* l) {
    __builtin_amdgcn_global_load_lds(
        (const __attribute__((address_space(1))) void*)g,
        (__attribute__((address_space(3))) void*)l,
        16, 0, 0);
}

// ---------------- privatized degree histogram: 8-bit LDS bins, non-atomic flush ----------------
__global__ __launch_bounds__(256) void k_histp(const int* __restrict__ src, const int* __restrict__ dst,
                                               unsigned char* __restrict__ tmp) {
    __shared__ unsigned lh[12512];   // 50048 bytes, 8-bit bins
    int chunk = blockIdx.x, r = blockIdx.y, which = blockIdx.z;
    const int* idx = (which ? dst : src) + (size_t)r * EE;
    for (int i = threadIdx.x; i < 12512; i += 256) lh[i] = 0;
    __syncthreads();
    int e0 = chunk * (EE / CHK);
    for (int e = e0 + threadIdx.x; e < e0 + EE / CHK; e += 256) {
        int n = idx[e];
        atomicAdd(&lh[n >> 2], 1u << ((n & 3) * 8));
    }
    __syncthreads();
    unsigned* t = (unsigned*)(tmp + (((size_t)(which * RR + r) * CHK + chunk) * 50048));
    for (int i = threadIdx.x; i < 12512; i += 256) t[i] = lh[i];
}

// ---------------- reduce the CHK private copies -> int degree arrays ----------------
__global__ void k_reduce(const unsigned char* __restrict__ tmp,
                         int* __restrict__ outdeg, int* __restrict__ indeg) {
    int i = blockIdx.x * 256 + threadIdx.x;
    if (i >= 2 * RR * 12512) return;
    int wr = i / 12512;        // which*RR + r
    int wd = i - wr * 12512;   // word index (4 nodes)
    unsigned s0 = 0, s1 = 0, s2 = 0, s3 = 0;
    const unsigned* base = (const unsigned*)(tmp + (size_t)wr * CHK * 50048) + wd;
    #pragma unroll
    for (int c = 0; c < CHK; c++) {
        unsigned v = base[(size_t)c * 12512];
        s0 += v & 255u; s1 += (v >> 8) & 255u; s2 += (v >> 16) & 255u; s3 += (v >> 24) & 255u;
    }
    int which = wr / RR, r = wr - which * RR;
    int n = wd * 4;
    int* deg = (which ? indeg : outdeg) + (size_t)r * NN;
    if (n < NN) {
        deg[n] = (int)s0;
        if (n + 1 < NN) deg[n + 1] = (int)s1;
        if (n + 2 < NN) deg[n + 2] = (int)s2;
        if (n + 3 < NN) deg[n + 3] = (int)s3;
    }
}

// ---------------- norms: in-place int degree -> float rsqrt ----------------
__global__ void k_norms(int* __restrict__ outdeg, int* __restrict__ indeg) {
    int i = blockIdx.x * blockDim.x + threadIdx.x;
    if (i >= RR * NN) return;
    int od = outdeg[i];
    int id = indeg[i];
    ((float*)outdeg)[i] = od > 0 ? rsqrtf((float)od) : 0.f;
    ((float*)indeg)[i]  = id > 0 ? rsqrtf((float)id) : 0.f;
}

// ---------------- parallel scan: phase A (per-block sums) ----------------
__global__ void k_scanA(const int* __restrict__ indeg, int* __restrict__ bsum) {
    int r = blockIdx.y;
    int i = blockIdx.x * 256 + threadIdx.x;
    int v = (i < NN) ? indeg[(size_t)r * NN + i] : 0;
    #pragma unroll
    for (int d = 32; d > 0; d >>= 1) v += __shfl_down(v, d, 64);
    __shared__ int ws4[4];
    if ((threadIdx.x & 63) == 0) ws4[threadIdx.x >> 6] = v;
    __syncthreads();
    if (threadIdx.x == 0) bsum[r * SCB + blockIdx.x] = ws4[0] + ws4[1] + ws4[2] + ws4[3];
}

// ---------------- phase B: exclusive scan of SCB block sums per relation ----------------
__global__ void k_scanB(int* __restrict__ bsum, int* __restrict__ offs) {
    int r = blockIdx.x;
    int t = threadIdx.x;
    int v = (t < SCB) ? bsum[r * SCB + t] : 0;
    int lane = t & 63, wid = t >> 6;
    int sv = v;
    #pragma unroll
    for (int d = 1; d < 64; d <<= 1) {
        int u = __shfl_up(sv, d, 64);
        if (lane >= d) sv += u;
    }
    __shared__ int wsum[4];
    if (lane == 63) wsum[wid] = sv;
    __syncthreads();
    int add = 0;
    for (int x = 0; x < wid; x++) add += wsum[x];
    int incl = sv + add;
    if (t < SCB) bsum[r * SCB + t] = incl - v;
    if (t == 255) offs[(size_t)r * (NN + 1) + NN] = incl;  // grand total
}

// ---------------- phase C: intra-block exclusive scan + base ----------------
__global__ void k_scanC(const int* __restrict__ indeg, const int* __restrict__ bsum,
                        int* __restrict__ offs) {
    int r = blockIdx.y;
    int i = blockIdx.x * 256 + threadIdx.x;
    int v = (i < NN) ? indeg[(size_t)r * NN + i] : 0;
    int lane = threadIdx.x & 63, wid = threadIdx.x >> 6;
    int sv = v;
    #pragma unroll
    for (int d = 1; d < 64; d <<= 1) {
        int u = __shfl_up(sv, d, 64);
        if (lane >= d) sv += u;
    }
    __shared__ int wsum[4];
    if (lane == 63) wsum[wid] = sv;
    __syncthreads();
    int add = bsum[r * SCB + blockIdx.x];
    for (int x = 0; x < wid; x++) add += wsum[x];
    if (i < NN) offs[(size_t)r * (NN + 1) + i] = sv - v + add;
}

// ---------------- fill CSR with fused src-norm weight (r4/r5 proven, 75us) ----------------
__global__ void k_fillw(const int* __restrict__ src, const int* __restrict__ dst,
                        const int* __restrict__ offs, const float* __restrict__ ns,
                        int* __restrict__ cursor, int2* __restrict__ csrw) {
    int i = blockIdx.x * blockDim.x + threadIdx.x;
    if (i >= RR * EE) return;
    int r = i / EE;
    int s = src[i], d = dst[i];
    int pos = offs[r * (NN + 1) + d] + atomicAdd(&cursor[r * NN + d], 1);
    int2 v;
    v.x = s;
    v.y = __float_as_int(ns[(size_t)r * NN + s]);
    csrw[(size_t)r * EE + pos] = v;
}

// ---------------- decoder prep (Mcat, cvec) + bias sums, one launch ----------------
__global__ void k_prep(const float* __restrict__ Wp1, const float* __restrict__ Wp2,
                       const float* __restrict__ bp1, const float* __restrict__ bp2,
                       const float* __restrict__ b2a, const float* __restrict__ b2b,
                       const float* __restrict__ b3a, const float* __restrict__ b3b,
                       float* __restrict__ Mcat, float* __restrict__ cvec,
                       float* __restrict__ bs) {
    int bx = blockIdx.x;
    if (bx < 16) {
        int t = bx * 256 + threadIdx.x;      // 4096 elements
        int i = t >> 4, j = t & 15;
        int half = j >> 3, jj = j & 7;
        const float* wrow = Wp1 + (size_t)(half * 256 + i) * 256;
        float s = 0.f;
        for (int k = 0; k < 256; k++) s += wrow[k] * Wp2[k * 8 + jj];
        Mcat[i * 16 + j] = s;
    } else if (bx == 16) {
        int j = threadIdx.x;
        if (j < 8) {
            float s = bp2[j];
            for (int k = 0; k < 256; k++) s += bp1[k] * Wp2[k * 8 + j];
            cvec[j] = s;
        }
    } else {
        int j = threadIdx.x;  // 256
        float s = 0.f;
        for (int r = 0; r < RR; r++) s += b2a[r * 256 + j];
        bs[j] = s;
        if (j < 128) {
            s = 0.f;
            for (int r = 0; r < RR; r++) s += b2b[r * 128 + j];
            bs[256 + j] = s;
        }
        s = 0.f;
        for (int r = 0; r < RR; r++) s += b3a[r * 256 + j];
        bs[512 + j] = s;
        if (j < 128) {
            s = 0.f;
            for (int r = 0; r < RR; r++) s += b3b[r * 128 + j];
            bs[768 + j] = s;
        }
    }
}

// ---------------- fold b-layer weights through decoder: FmatT[128][512] bf16, cfold[16] ----
__global__ void k_fold(const float* __restrict__ W2b, const float* __restrict__ W3b,
                       const float* __restrict__ Mcat, const float* __restrict__ bs,
                       unsigned short* __restrict__ FmatT, float* __restrict__ cfold) {
    int bx = blockIdx.x;
    if (bx < 256) {
        int idx = bx * 256 + threadIdx.x;      // 65536 = 128 rows x 512 cols
        int rj = idx >> 9, i = idx & 511;
        int r = rj >> 4, j = rj & 15;
        float s = 0.f;
        if (i < 256) {
            const float* wr = W2b + ((size_t)r * 256 + i) * 128;
            for (int c = 0; c < 128; c++) s += wr[c] * Mcat[c * 16 + j];
        } else {
            const float* wr = W3b + ((size_t)r * 256 + (i - 256)) * 128;
            for (int c = 0; c < 128; c++) s += wr[c] * Mcat[(128 + c) * 16 + j];
        }
        FmatT[(size_t)rj * 512 + i] = f2bf(s);
    } else {
        int j = threadIdx.x;
        if (j < 16) {
            float s = 0.f;
            for (int c = 0; c < 128; c++)
                s += bs[256 + c] * Mcat[c * 16 + j] + bs[768 + c] * Mcat[(128 + c) * 16 + j];
            cfold[j] = s;
        }
    }
}

// ---------------- interleaved bf16 cast: XH[m] = [x2(256) | x3(300) | 0 x4], stride 560 ----
__global__ void k_castx(const float* __restrict__ x2, const float* __restrict__ x3,
                        unsigned short* __restrict__ XH) {
    int i = blockIdx.x * 256 + threadIdx.x;
    if (i >= NN * 560) return;
    int row = i / 560, col = i - row * 560;
    float v;
    if (col < 256) v = x2[(size_t)row * 256 + col];
    else if (col < 556) v = x3[(size_t)row * 300 + (col - 256)];
    else v = 0.f;
    XH[i] = f2bf(v);
}

// ---------------- weight transposes (a-layers only): WT[n][r][kpad] bf16 ----------------
__global__ void k_wt2(const float* __restrict__ W2a, const float* __restrict__ W3a,
                      unsigned short* __restrict__ WT2, unsigned short* __restrict__ WT3) {
    const float* W; unsigned short* WT; int K0, Kpad;
    if (blockIdx.y == 0) { W = W2a; WT = WT2; K0 = 256; Kpad = 256; }
    else                 { W = W3a; WT = WT3; K0 = 300; Kpad = 304; }
    int i = blockIdx.x * 256 + threadIdx.x;
    int total = 256 * RR * Kpad;
    if (i >= total) return;
    int n = i / (RR * Kpad);
    int rem = i - n * (RR * Kpad);
    int r = rem / Kpad;
    int k = rem - r * Kpad;
    float v = (k < K0) ? W[((size_t)r * K0 + k) * 256 + n] : 0.f;
    WT[i] = f2bf(v);
}

// ---------------- dual-payload aggregation v4: whole-wave row loads (r6, kept) ----------------
__global__ __launch_bounds__(256) void k_aggp(
        const unsigned short* __restrict__ xb,
        const int2* __restrict__ csrw, const int* __restrict__ offs,
        const float* __restrict__ nd, int nbase,
        unsigned short* __restrict__ Y2, unsigned short* __restrict__ Y3) {
    int lane = threadIdx.x & 63;
    int sub = threadIdx.x >> 6;
    int bn = blockIdx.x * 4 + sub;
    int n = nbase + bn;
    int r = blockIdx.y;
    int o0 = offs[r * (NN + 1) + n];
    int o1 = offs[r * (NN + 1) + n + 1];
    o0 = __builtin_amdgcn_readfirstlane(o0);
    o1 = __builtin_amdgcn_readfirstlane(o1);
    int cnt = o1 - o0;
    float ndv = nd[(size_t)r * NN + n];
    const int2* cs = csrw + (size_t)r * EE + o0;
    bool tl = lane < 6;          // tail cols 512..559
    float va[8], vc[8];
    #pragma unroll
    for (int q = 0; q < 8; q++) { va[q] = 0.f; vc[q] = 0.f; }

    for (int eb = 0; eb < cnt; eb += 64) {
        int rem = cnt - eb;                        // > 0
        int2 rec = cs[eb + min(lane, rem - 1)];    // coalesced record block
        int kmax = rem < 64 ? rem : 64;
        for (int kb = 0; kb < kmax; kb += 4) {
            #pragma unroll
            for (int u = 0; u < 4; u++) {
                int k = kb + u;
                if (k >= kmax) break;              // wave-uniform
                int sidx = __shfl(rec.x, k, 64);
                float f = __int_as_float(__shfl(rec.y, k, 64));
                const unsigned short* p = xb + (size_t)(unsigned)sidx * 560;
                short8 M = *(const short8*)(p + lane * 8);
                #pragma unroll
                for (int q = 0; q < 8; q++) va[q] += f * bf2f((unsigned short)M[q]);
                if (tl) {
                    short8 C = *(const short8*)(p + 512 + lane * 8);
                    #pragma unroll
                    for (int q = 0; q < 8; q++) vc[q] += f * bf2f((unsigned short)C[q]);
                }
            }
        }
    }
    short8 o;
    #pragma unroll
    for (int q = 0; q < 8; q++) o[q] = (short)f2bf(va[q] * ndv);
    if (lane < 32) {
        *(short8*)(Y2 + (size_t)bn * 2048 + r * 256 + lane * 8) = o;
    } else {
        *(short8*)(Y3 + (size_t)bn * 2432 + r * 304 + (lane - 32) * 8) = o;
    }
    if (tl) {
        short8 oc;
        #pragma unroll
        for (int q = 0; q < 8; q++) oc[q] = (short)f2bf(vc[q] * ndv);
        *(short8*)(Y3 + (size_t)bn * 2432 + r * 304 + 256 + lane * 8) = oc;
    }
}

// ---------------- generic bf16 MFMA GEMM (r0-proven), used for G projection ----------------
// flags: 1=addbias, 2=accum(read Cin fp32), 4=relu, 8=out bf16 (else fp32)
template<int TN>
__global__ __launch_bounds__(256) void k_gemm_bf(
        const unsigned short* __restrict__ A, int lda,
        const unsigned short* __restrict__ BT, int ldb,
        const float* __restrict__ bias,
        const float* __restrict__ Cin, int ldcin,
        void* __restrict__ Cout, int ldc,
        int M, int K, int flags) {
    constexpr int BN = TN * 32;
    __shared__ unsigned short As[128 * 64];
    __shared__ unsigned short Bs[BN * 64];
    int m0 = blockIdx.x * 128;
    int n0 = blockIdx.y * BN;
    int t = threadIdx.x;
    int w = t >> 6, l = t & 63;
    int qm = (w >> 1) * 64, qn = (w & 1) * (TN * 16);
    int lr = l & 15, lg = l >> 4;
    int lrow = l >> 3;
    int lch  = (l & 7) ^ lrow;

    floatx4 acc[4][TN];
    #pragma unroll
    for (int a = 0; a < 4; a++)
        #pragma unroll
        for (int b = 0; b < TN; b++)
            acc[a][b] = (floatx4){0.f, 0.f, 0.f, 0.f};

    for (int k0 = 0; k0 < K; k0 += 64) {
        #pragma unroll
        for (int j = 0; j < 4; j++) {
            int seg = w * 4 + j;
            int gr = m0 + seg * 8 + lrow; if (gr > M - 1) gr = M - 1;
            gload_lds16(A + (size_t)gr * lda + k0 + lch * 8, &As[seg * 512]);
        }
        #pragma unroll
        for (int j = 0; j < TN; j++) {
            int seg = w * TN + j;
            int row = n0 + seg * 8 + lrow;
            gload_lds16(BT + (size_t)row * ldb + k0 + lch * 8, &Bs[seg * 512]);
        }
        __syncthreads();
        #pragma unroll
        for (int ks = 0; ks < 2; ks++) {
            int slot = ((ks * 4 + lg) ^ (lr & 7)) * 8;
            short8 af[4], bf[TN];
            #pragma unroll
            for (int i = 0; i < 4; i++)
                af[i] = *(const short8*)&As[(qm + i * 16 + lr) * 64 + slot];
            #pragma unroll
            for (int i = 0; i < TN; i++)
                bf[i] = *(const short8*)&Bs[(qn + i * 16 + lr) * 64 + slot];
            #pragma unroll
            for (int tm = 0; tm < 4; tm++)
                #pragma unroll
                for (int tn = 0; tn < TN; tn++)
                    acc[tm][tn] = __builtin_amdgcn_mfma_f32_16x16x32_bf16(
                        af[tm], bf[tn], acc[tm][tn], 0, 0, 0);
        }
        __syncthreads();
    }

    int addbias = flags & 1, accum = flags & 2, relu = flags & 4, outbf = flags & 8;
    #pragma unroll
    for (int tm = 0; tm < 4; tm++) {
        int rbase = m0 + qm + tm * 16 + lg * 4;
        #pragma unroll
        for (int reg = 0; reg < 4; reg++) {
            int row = rbase + reg;
            if (row >= M) continue;
            #pragma unroll
            for (int tn = 0; tn < TN; tn++) {
                int col = n0 + qn + tn * 16 + lr;
                float v = acc[tm][tn][reg];
                if (addbias) v += bias[col];
                if (accum) v += Cin[(size_t)row * ldcin + col];
                if (relu) v = fmaxf(v, 0.f);
                if (outbf) ((unsigned short*)Cout)[(size_t)row * ldc + col] = f2bf(v);
                else       ((float*)Cout)[(size_t)row * ldc + col] = v;
            }
        }
    }
}

// ---------------- paired a-layer GEMM, BM=64/BN=64, XCD-swizzled sibling n-tiles -------------
// 1D grid 640. Decode: g=(x>>5)*8+(x&7) in [0,160) -> (z, m-block); nb=(x>>3)&3.
// The 4 n-siblings of a group get ids {base, base+8, base+16, base+24} == same id mod 8
// -> same XCD (round-robin dispatch) -> A-tile (256 KB) read once from LLC, 3x from L2.
__global__ __launch_bounds__(256) void k_gemm2(
        const unsigned short* __restrict__ Y2, const unsigned short* __restrict__ Y3,
        const unsigned short* __restrict__ WT2, const unsigned short* __restrict__ WT3,
        const float* __restrict__ bs, unsigned short* __restrict__ hb,
        int nbase, int M) {
    __shared__ unsigned short As[64 * 64];
    __shared__ unsigned short Bs[64 * 64];
    int x = blockIdx.x;
    int g = (x >> 5) * 8 + (x & 7);
    int nb = (x >> 3) & 3;
    if (g >= 158) return;          // 158 = 2 z * 79 m-blocks
    int z = g / 79;
    int mb = g - z * 79;
    const unsigned short* A  = z ? Y3 : Y2;
    const unsigned short* BT = z ? WT3 : WT2;
    int lda = z ? 2432 : 2048;
    int K = lda;
    const float* bias = bs + z * 512;
    int m0 = mb * 64;
    int n0 = nb * 64;
    int t = threadIdx.x;
    int w = t >> 6, l = t & 63;
    int qm = (w >> 1) * 32, qn = (w & 1) * 32;
    int lr = l & 15, lg = l >> 4;
    int lrow = l >> 3;
    int lch  = (l & 7) ^ lrow;

    floatx4 acc[2][2];
    #pragma unroll
    for (int a = 0; a < 2; a++)
        #pragma unroll
        for (int b = 0; b < 2; b++)
            acc[a][b] = (floatx4){0.f, 0.f, 0.f, 0.f};

    for (int k0 = 0; k0 < K; k0 += 64) {
        #pragma unroll
        for (int j = 0; j < 2; j++) {
            int seg = w * 2 + j;                   // 8 segs x 8 rows = 64 rows
            int gr = m0 + seg * 8 + lrow; if (gr > M - 1) gr = M - 1;
            gload_lds16(A + (size_t)gr * lda + k0 + lch * 8, &As[seg * 512]);
        }
        #pragma unroll
        for (int j = 0; j < 2; j++) {
            int seg = w * 2 + j;
            int row = n0 + seg * 8 + lrow;         // <= 255, WT has 256 rows
            gload_lds16(BT + (size_t)row * lda + k0 + lch * 8, &Bs[seg * 512]);
        }
        __syncthreads();
        #pragma unroll
        for (int ks = 0; ks < 2; ks++) {
            int slot = ((ks * 4 + lg) ^ (lr & 7)) * 8;
            short8 af[2], bf[2];
            #pragma unroll
            for (int i = 0; i < 2; i++)
                af[i] = *(const short8*)&As[(qm + i * 16 + lr) * 64 + slot];
            #pragma unroll
            for (int i = 0; i < 2; i++)
                bf[i] = *(const short8*)&Bs[(qn + i * 16 + lr) * 64 + slot];
            #pragma unroll
            for (int tm = 0; tm < 2; tm++)
                #pragma unroll
                for (int tn = 0; tn < 2; tn++)
                    acc[tm][tn] = __builtin_amdgcn_mfma_f32_16x16x32_bf16(
                        af[tm], bf[tn], acc[tm][tn], 0, 0, 0);
        }
        __syncthreads();
    }

    #pragma unroll
    for (int tm = 0; tm < 2; tm++) {
        int rbase = m0 + qm + tm * 16 + lg * 4;
        #pragma unroll
        for (int reg = 0; reg < 4; reg++) {
            int row = rbase + reg;
            if (row >= M) continue;
            #pragma unroll
            for (int tn = 0; tn < 2; tn++) {
                int col = n0 + qn + tn * 16 + lr;
                float v = fmaxf(acc[tm][tn][reg] + bias[col], 0.f);
                hb[(size_t)(nbase + row) * 512 + z * 256 + col] = f2bf(v);
            }
        }
    }
}

// ---------------- 16-dim projected aggregation v2: slot = relation pairs, rec-broadcast ------
__global__ __launch_bounds__(256) void k_aggAB(
        const int2* __restrict__ csrw, const int* __restrict__ offs,
        const float* __restrict__ nd, const float* __restrict__ G,
        const float* __restrict__ cfold, const float* __restrict__ cvec,
        float* __restrict__ AB) {
    int lane = threadIdx.x & 63, sub = threadIdx.x >> 6;
    int n = blockIdx.x * 4 + sub;
    int slot = lane >> 4, j = lane & 15;
    int jb = slot << 4;                     // group base lane for shfl
    float acc = 0.f;
    for (int hh = 0; hh < 2; hh++) {
        int r = slot + hh * 4;
        int o0 = offs[r * (NN + 1) + n];
        int o1 = offs[r * (NN + 1) + n + 1];
        float ndv = nd[(size_t)r * NN + n];
        const int2* cs = csrw + (size_t)r * EE + o0;
        int cnt = o1 - o0;
        float t0 = 0.f, t1 = 0.f;
        for (int eb = 0; eb < cnt; eb += 16) {
            int rem = cnt - eb;
            int2 rec = cs[eb + min(j, rem - 1)];   // 16 records per slot, coalesced
            int kmax = rem < 16 ? rem : 16;
            for (int k = 0; k < kmax; k += 2) {
                int s0 = __shfl(rec.x, jb + k, 64);
                float f0 = __int_as_float(__shfl(rec.y, jb + k, 64));
                int k1 = k + 1 < kmax ? k + 1 : kmax - 1;
                int s1 = __shfl(rec.x, jb + k1, 64);
                float f1 = (k + 1 < kmax) ? __int_as_float(__shfl(rec.y, jb + k1, 64)) : 0.f;
                t0 += f0 * G[(size_t)(unsigned)s0 * 128 + r * 16 + j];
                t1 += f1 * G[(size_t)(unsigned)s1 * 128 + r * 16 + j];
            }
        }
        acc += ndv * (t0 + t1);
    }
    acc += __shfl_xor(acc, 16, 64);
    acc += __shfl_xor(acc, 32, 64);
    if (lane < 16) AB[(size_t)n * 16 + j] = acc + cfold[j] + (j < 8 ? cvec[j] : 0.f);
}

// ---------------- per-edge decoder (float4, cvec pre-folded) ----------------
__global__ void k_dec(const int* __restrict__ dsrc, const int* __restrict__ ddst,
                      const float* __restrict__ AB, float* __restrict__ out) {
    int e = blockIdx.x * 256 + threadIdx.x;
    if (e >= EDD) return;
    int s = dsrc[e], d = ddst[e];
    const float4* as = (const float4*)(AB + (size_t)s * 16);
    const float4* ad = (const float4*)(AB + (size_t)d * 16 + 8);
    float4 x0 = as[0], x1 = as[1], y0 = ad[0], y1 = ad[1];
    float4 o0 = {x0.x + y0.x, x0.y + y0.y, x0.z + y0.z, x0.w + y0.w};
    float4 o1 = {x1.x + y1.x, x1.y + y1.y, x1.z + y1.z, x1.w + y1.w};
    float4* op = (float4*)(out + (size_t)e * 8);
    op[0] = o0; op[1] = o1;
}

extern "C" void kernel_launch(void* const* d_in, const int* in_sizes, int n_in,
                              void* d_out, int out_size, void* d_ws, size_t ws_size,
                              hipStream_t stream) {
    const float* x2  = (const float*)d_in[0];
    const float* x3  = (const float*)d_in[1];
    const int*   src = (const int*)d_in[2];
    const int*   dst = (const int*)d_in[3];
    const int*   dsrc = (const int*)d_in[4];
    const int*   ddst = (const int*)d_in[5];
    const float* W2a = (const float*)d_in[6];
    const float* b2a = (const float*)d_in[7];
    const float* W2b = (const float*)d_in[8];
    const float* b2b = (const float*)d_in[9];
    const float* W3a = (const float*)d_in[10];
    const float* b3a = (const float*)d_in[11];
    const float* W3b = (const float*)d_in[12];
    const float* b3b = (const float*)d_in[13];
    const float* Wp1 = (const float*)d_in[14];
    const float* bp1 = (const float*)d_in[15];
    const float* Wp2 = (const float*)d_in[16];
    const float* bp2 = (const float*)d_in[17];
    float* out = (float*)d_out;

    // ---- workspace layout (~172 MB < proven 182.4 MB bound) ----
    char* ws = (char*)d_ws;
    size_t off = 0;
    auto alloc = [&](size_t nbytes) {
        char* p = ws + off;
        off += nbytes;
        off = (off + 255) & ~(size_t)255;
        return p;
    };
    float* ns   = (float*)alloc((size_t)RR * NN * 4);        // aliases outdeg
    float* nd   = (float*)alloc((size_t)RR * NN * 4);        // aliases indeg
    int*   offs = (int*)alloc((size_t)RR * (NN + 1) * 4);
    int2*  csrw = (int2*)alloc((size_t)RR * EE * 8);
    unsigned short* XH     = (unsigned short*)alloc((size_t)NN * 560 * 2);  // [x2|x3|pad] interleaved
    unsigned short* hbuf23 = (unsigned short*)alloc((size_t)NN * 512 * 2);  // [h2a|h3a] interleaved
    unsigned short* WT2a   = (unsigned short*)alloc((size_t)256 * 2048 * 2);
    unsigned short* WT3a   = (unsigned short*)alloc((size_t)256 * 2432 * 2);
    unsigned short* FmatT  = (unsigned short*)alloc((size_t)128 * 512 * 2);
    char* YR = alloc((size_t)CH * (2048 + 2432) * 2);        // Y2a|Y3a; also cursor/htmp/G/AB
    float* Mcat  = (float*)alloc(4096 * 4);
    float* cvec  = (float*)alloc(64 * 4);
    float* bsums = (float*)alloc(1024 * 4);
    float* cfold = (float*)alloc(64 * 4);
    int*   bsum  = (int*)alloc((size_t)RR * SCB * 4);

    unsigned short* Y2a = (unsigned short*)YR;
    unsigned short* Y3a = Y2a + (size_t)CH * 2048;
    int*   outdeg = (int*)ns;
    int*   indeg  = (int*)nd;
    int*   cursor = (int*)YR;                               // 1.6 MB, live only until k_fillw
    unsigned char* htmp = (unsigned char*)(YR + (4 << 20)); // 12.8 MB, live during histp/reduce
    float* G      = (float*)YR;                             // [NN x 128] f32, live after phase a
    float* AB     = (float*)(YR + (size_t)NN * 128 * 4);    // 3.2 MB after G

    // ---- graph prep ----
    hipMemsetAsync(cursor, 0, (size_t)RR * NN * 4, stream);

    k_histp<<<dim3(CHK, RR, 2), 256, 0, stream>>>(src, dst, htmp);
    k_reduce<<<(2 * RR * 12512 + 255) / 256, 256, 0, stream>>>(htmp, outdeg, indeg);
    k_scanA<<<dim3(SCB, RR), 256, 0, stream>>>(indeg, bsum);
    k_scanB<<<RR, 256, 0, stream>>>(bsum, offs);
    k_scanC<<<dim3(SCB, RR), 256, 0, stream>>>(indeg, bsum, offs);
    k_norms<<<(RR * NN + 255) / 256, 256, 0, stream>>>(outdeg, indeg);
    int edgeBlocks = (RR * EE + 255) / 256;
    k_fillw<<<edgeBlocks, 256, 0, stream>>>(src, dst, offs, ns, cursor, csrw);
    k_prep<<<18, 256, 0, stream>>>(Wp1, Wp2, bp1, bp2, b2a, b2b, b3a, b3b, Mcat, cvec, bsums);
    k_fold<<<257, 256, 0, stream>>>(W2b, W3b, Mcat, bsums, FmatT, cfold);

    k_castx<<<(NN * 560 + 255) / 256, 256, 0, stream>>>(x2, x3, XH);
    k_wt2<<<dim3((256 * RR * 304 + 255) / 256, 2), 256, 0, stream>>>(W2a, W3a, WT2a, WT3a);

    // ---- phase a: chunked dual aggregation + paired GEMM -> hbuf23 (relu bf16) ----
    for (int c = 0; c < NN / CH; c++) {
        k_aggp<<<dim3(CH / 4, RR), 256, 0, stream>>>(XH, csrw, offs, nd, c * CH, Y2a, Y3a);
        k_gemm2<<<640, 256, 0, stream>>>(
            Y2a, Y3a, WT2a, WT3a, bsums, hbuf23, c * CH, CH);
    }

    // ---- phase b (folded): G = hbuf23 @ FmatT^T  [NN x 128] f32 ----
    k_gemm_bf<1><<<dim3((NN + 127) / 128, 4), 256, 0, stream>>>(
        hbuf23, 512, FmatT, 512, bsums, (const float*)nullptr, 0,
        (void*)G, 128, NN, 512, 0);

    // ---- projected aggregation -> AB, then decoder ----
    k_aggAB<<<NN / 4, 256, 0, stream>>>(csrw, offs, nd, G, cfold, cvec, AB);
    k_dec<<<(EDD + 255) / 256, 256, 0, stream>>>(dsrc, ddst, AB, out);
}

// Round 9
// 1051.650 us; speedup vs baseline: 1.3496x; 1.0021x over previous
//
#include <hip/hip_runtime.h>
#include <hip/hip_bf16.h>

#define NN 50000
#define RR 8
#define EE 200000
#define EDD 400000
#define SCB 196   // ceil(NN/256) scan blocks
#define CH 5000   // phase-a node chunk (10 chunks)
#define CHK 16    // histogram privatization chunks

typedef __attribute__((ext_vector_type(8))) short short8;
typedef __attribute__((ext_vector_type(4))) float floatx4;

static __device__ __forceinline__ unsigned short f2bf(float f) {
    union { float f; unsigned u; } v; v.f = f;
    unsigned r = v.u + 0x7fff + ((v.u >> 16) & 1);
    return (unsigned short)(r >> 16);
}
static __device__ __forceinline__ float bf2f(unsigned short h) {
    union { unsigned u; float f; } v; v.u = ((unsigned)h) << 16;
    return v.f;
}
// async global->LDS, 16B per lane; LDS dest = uniform base + lane*16
static __device__ __forceinline__ void gload_lds16(const unsigned short* g, unsigned short* l) {
    __builtin_amdgcn_global_load_lds(
        (const __attribute__((address_space(1))) void*)g,
        (__attribute__((address_space(3))) void*)l,
        16, 0, 0);
}

// ---------------- privatized degree histogram: 8-bit LDS bins, non-atomic flush ----------------
__global__ __launch_bounds__(256) void k_histp(const int* __restrict__ src, const int* __restrict__ dst,
                                               unsigned char* __restrict__ tmp) {
    __shared__ unsigned lh[12512];   // 50048 bytes, 8-bit bins
    int chunk = blockIdx.x, r = blockIdx.y, which = blockIdx.z;
    const int* idx = (which ? dst : src) + (size_t)r * EE;
    for (int i = threadIdx.x; i < 12512; i += 256) lh[i] = 0;
    __syncthreads();
    int e0 = chunk * (EE / CHK);
    for (int e = e0 + threadIdx.x; e < e0 + EE / CHK; e += 256) {
        int n = idx[e];
        atomicAdd(&lh[n >> 2], 1u << ((n & 3) * 8));
    }
    __syncthreads();
    unsigned* t = (unsigned*)(tmp + (((size_t)(which * RR + r) * CHK + chunk) * 50048));
    for (int i = threadIdx.x; i < 12512; i += 256) t[i] = lh[i];
}

// ---------------- reduce the CHK private copies -> int degree arrays ----------------
__global__ void k_reduce(const unsigned char* __restrict__ tmp,
                         int* __restrict__ outdeg, int* __restrict__ indeg) {
    int i = blockIdx.x * 256 + threadIdx.x;
    if (i >= 2 * RR * 12512) return;
    int wr = i / 12512;        // which*RR + r
    int wd = i - wr * 12512;   // word index (4 nodes)
    unsigned s0 = 0, s1 = 0, s2 = 0, s3 = 0;
    const unsigned* base = (const unsigned*)(tmp + (size_t)wr * CHK * 50048) + wd;
    #pragma unroll
    for (int c = 0; c < CHK; c++) {
        unsigned v = base[(size_t)c * 12512];
        s0 += v & 255u; s1 += (v >> 8) & 255u; s2 += (v >> 16) & 255u; s3 += (v >> 24) & 255u;
    }
    int which = wr / RR, r = wr - which * RR;
    int n = wd * 4;
    int* deg = (which ? indeg : outdeg) + (size_t)r * NN;
    if (n < NN) {
        deg[n] = (int)s0;
        if (n + 1 < NN) deg[n + 1] = (int)s1;
        if (n + 2 < NN) deg[n + 2] = (int)s2;
        if (n + 3 < NN) deg[n + 3] = (int)s3;
    }
}

// ---------------- norms: in-place int degree -> float rsqrt ----------------
__global__ void k_norms(int* __restrict__ outdeg, int* __restrict__ indeg) {
    int i = blockIdx.x * blockDim.x + threadIdx.x;
    if (i >= RR * NN) return;
    int od = outdeg[i];
    int id = indeg[i];
    ((float*)outdeg)[i] = od > 0 ? rsqrtf((float)od) : 0.f;
    ((float*)indeg)[i]  = id > 0 ? rsqrtf((float)id) : 0.f;
}

// ---------------- parallel scan: phase A (per-block sums) ----------------
__global__ void k_scanA(const int* __restrict__ indeg, int* __restrict__ bsum) {
    int r = blockIdx.y;
    int i = blockIdx.x * 256 + threadIdx.x;
    int v = (i < NN) ? indeg[(size_t)r * NN + i] : 0;
    #pragma unroll
    for (int d = 32; d > 0; d >>= 1) v += __shfl_down(v, d, 64);
    __shared__ int ws4[4];
    if ((threadIdx.x & 63) == 0) ws4[threadIdx.x >> 6] = v;
    __syncthreads();
    if (threadIdx.x == 0) bsum[r * SCB + blockIdx.x] = ws4[0] + ws4[1] + ws4[2] + ws4[3];
}

// ---------------- phase B: exclusive scan of SCB block sums per relation ----------------
__global__ void k_scanB(int* __restrict__ bsum, int* __restrict__ offs) {
    int r = blockIdx.x;
    int t = threadIdx.x;
    int v = (t < SCB) ? bsum[r * SCB + t] : 0;
    int lane = t & 63, wid = t >> 6;
    int sv = v;
    #pragma unroll
    for (int d = 1; d < 64; d <<= 1) {
        int u = __shfl_up(sv, d, 64);
        if (lane >= d) sv += u;
    }
    __shared__ int wsum[4];
    if (lane == 63) wsum[wid] = sv;
    __syncthreads();
    int add = 0;
    for (int x = 0; x < wid; x++) add += wsum[x];
    int incl = sv + add;
    if (t < SCB) bsum[r * SCB + t] = incl - v;
    if (t == 255) offs[(size_t)r * (NN + 1) + NN] = incl;  // grand total
}

// ---------------- phase C: intra-block exclusive scan + base ----------------
__global__ void k_scanC(const int* __restrict__ indeg, const int* __restrict__ bsum,
                        int* __restrict__ offs) {
    int r = blockIdx.y;
    int i = blockIdx.x * 256 + threadIdx.x;
    int v = (i < NN) ? indeg[(size_t)r * NN + i] : 0;
    int lane = threadIdx.x & 63, wid = threadIdx.x >> 6;
    int sv = v;
    #pragma unroll
    for (int d = 1; d < 64; d <<= 1) {
        int u = __shfl_up(sv, d, 64);
        if (lane >= d) sv += u;
    }
    __shared__ int wsum[4];
    if (lane == 63) wsum[wid] = sv;
    __syncthreads();
    int add = bsum[r * SCB + blockIdx.x];
    for (int x = 0; x < wid; x++) add += wsum[x];
    if (i < NN) offs[(size_t)r * (NN + 1) + i] = sv - v + add;
}

// ---------------- CSR fill v3: XCD-range partitioned, line-assembling writes ----------------
// grid (8 ranges fastest, RR, 8 chunks) = 512 blocks; linear id % 8 == range -> all writers of
// a 6250-node dst range sit on ONE XCD -> its L2 assembles full 64B CSR lines (r5/r7 counter:
// 64B/record writeback = 101 MB for 12.8 MB logical). Edge slices re-read 8x but LLC-served.
// r6 failure mode (64 blocks, 2.75% occ) addressed: 512 blocks, global cursor (proven cheap).
__global__ __launch_bounds__(256) void k_fillw3(const int* __restrict__ src, const int* __restrict__ dst,
                                                const int* __restrict__ offs, const float* __restrict__ ns,
                                                int* __restrict__ cursor, int2* __restrict__ csrw) {
    int range = blockIdx.x, r = blockIdx.y, chunk = blockIdx.z;
    int lo = range * 6250;
    const int4* sp = (const int4*)(src + (size_t)r * EE);
    const int4* dp = (const int4*)(dst + (size_t)r * EE);
    const int* offr = offs + r * (NN + 1);
    const float* nsr = ns + (size_t)r * NN;
    int* cur = cursor + r * NN;
    int2* cw = csrw + (size_t)r * EE;
    int e40 = chunk * (EE / 32);             // 6250 int4 per chunk
    for (int e4 = e40 + threadIdx.x; e4 < e40 + EE / 32; e4 += 256) {
        int4 d4 = dp[e4];
        int4 s4 = sp[e4];
        #pragma unroll
        for (int u = 0; u < 4; u++) {
            int d = (u == 0 ? d4.x : u == 1 ? d4.y : u == 2 ? d4.z : d4.w) - lo;
            if ((unsigned)d < 6250u) {
                int s = (u == 0 ? s4.x : u == 1 ? s4.y : u == 2 ? s4.z : s4.w);
                int pos = offr[lo + d] + atomicAdd(&cur[lo + d], 1);
                int2 v;
                v.x = s;
                v.y = __float_as_int(nsr[s]);
                cw[pos] = v;
            }
        }
    }
}

// ---------------- decoder prep (Mcat, cvec) + bias sums, one launch ----------------
__global__ void k_prep(const float* __restrict__ Wp1, const float* __restrict__ Wp2,
                       const float* __restrict__ bp1, const float* __restrict__ bp2,
                       const float* __restrict__ b2a, const float* __restrict__ b2b,
                       const float* __restrict__ b3a, const float* __restrict__ b3b,
                       float* __restrict__ Mcat, float* __restrict__ cvec,
                       float* __restrict__ bs) {
    int bx = blockIdx.x;
    if (bx < 16) {
        int t = bx * 256 + threadIdx.x;      // 4096 elements
        int i = t >> 4, j = t & 15;
        int half = j >> 3, jj = j & 7;
        const float* wrow = Wp1 + (size_t)(half * 256 + i) * 256;
        float s = 0.f;
        for (int k = 0; k < 256; k++) s += wrow[k] * Wp2[k * 8 + jj];
        Mcat[i * 16 + j] = s;
    } else if (bx == 16) {
        int j = threadIdx.x;
        if (j < 8) {
            float s = bp2[j];
            for (int k = 0; k < 256; k++) s += bp1[k] * Wp2[k * 8 + j];
            cvec[j] = s;
        }
    } else {
        int j = threadIdx.x;  // 256
        float s = 0.f;
        for (int r = 0; r < RR; r++) s += b2a[r * 256 + j];
        bs[j] = s;
        if (j < 128) {
            s = 0.f;
            for (int r = 0; r < RR; r++) s += b2b[r * 128 + j];
            bs[256 + j] = s;
        }
        s = 0.f;
        for (int r = 0; r < RR; r++) s += b3a[r * 256 + j];
        bs[512 + j] = s;
        if (j < 128) {
            s = 0.f;
            for (int r = 0; r < RR; r++) s += b3b[r * 128 + j];
            bs[768 + j] = s;
        }
    }
}

// ---------------- fold b-layer weights through decoder: FmatT[128][512] bf16, cfold[16] ----
__global__ void k_fold(const float* __restrict__ W2b, const float* __restrict__ W3b,
                       const float* __restrict__ Mcat, const float* __restrict__ bs,
                       unsigned short* __restrict__ FmatT, float* __restrict__ cfold) {
    int bx = blockIdx.x;
    if (bx < 256) {
        int idx = bx * 256 + threadIdx.x;      // 65536 = 128 rows x 512 cols
        int rj = idx >> 9, i = idx & 511;
        int r = rj >> 4, j = rj & 15;
        float s = 0.f;
        if (i < 256) {
            const float* wr = W2b + ((size_t)r * 256 + i) * 128;
            for (int c = 0; c < 128; c++) s += wr[c] * Mcat[c * 16 + j];
        } else {
            const float* wr = W3b + ((size_t)r * 256 + (i - 256)) * 128;
            for (int c = 0; c < 128; c++) s += wr[c] * Mcat[(128 + c) * 16 + j];
        }
        FmatT[(size_t)rj * 512 + i] = f2bf(s);
    } else {
        int j = threadIdx.x;
        if (j < 16) {
            float s = 0.f;
            for (int c = 0; c < 128; c++)
                s += bs[256 + c] * Mcat[c * 16 + j] + bs[768 + c] * Mcat[(128 + c) * 16 + j];
            cfold[j] = s;
        }
    }
}

// ---------------- interleaved bf16 cast, vectorized: thread = one short8 of XH ----------------
__global__ void k_castx(const float* __restrict__ x2, const float* __restrict__ x3,
                        unsigned short* __restrict__ XH) {
    int i = blockIdx.x * 256 + threadIdx.x;
    if (i >= NN * 70) return;
    int row = i / 70, oc = (i - row * 70) * 8;
    short8 o;
    if (oc < 256) {
        const float4* p = (const float4*)(x2 + (size_t)row * 256 + oc);
        float4 a = p[0], b = p[1];
        o[0] = (short)f2bf(a.x); o[1] = (short)f2bf(a.y);
        o[2] = (short)f2bf(a.z); o[3] = (short)f2bf(a.w);
        o[4] = (short)f2bf(b.x); o[5] = (short)f2bf(b.y);
        o[6] = (short)f2bf(b.z); o[7] = (short)f2bf(b.w);
    } else if (oc < 552) {
        const float4* p = (const float4*)(x3 + (size_t)row * 300 + (oc - 256));
        float4 a = p[0], b = p[1];
        o[0] = (short)f2bf(a.x); o[1] = (short)f2bf(a.y);
        o[2] = (short)f2bf(a.z); o[3] = (short)f2bf(a.w);
        o[4] = (short)f2bf(b.x); o[5] = (short)f2bf(b.y);
        o[6] = (short)f2bf(b.z); o[7] = (short)f2bf(b.w);
    } else {   // oc == 552: x3 cols 296..299 + 4 zero pad
        const float* p = x3 + (size_t)row * 300 + 296;
        o[0] = (short)f2bf(p[0]); o[1] = (short)f2bf(p[1]);
        o[2] = (short)f2bf(p[2]); o[3] = (short)f2bf(p[3]);
        o[4] = 0; o[5] = 0; o[6] = 0; o[7] = 0;
    }
    *(short8*)(XH + (size_t)row * 560 + oc) = o;
}

// ---------------- weight transposes (a-layers only): WT[n][r][kpad] bf16 ----------------
__global__ void k_wt2(const float* __restrict__ W2a, const float* __restrict__ W3a,
                      unsigned short* __restrict__ WT2, unsigned short* __restrict__ WT3) {
    const float* W; unsigned short* WT; int K0, Kpad;
    if (blockIdx.y == 0) { W = W2a; WT = WT2; K0 = 256; Kpad = 256; }
    else                 { W = W3a; WT = WT3; K0 = 300; Kpad = 304; }
    int i = blockIdx.x * 256 + threadIdx.x;
    int total = 256 * RR * Kpad;
    if (i >= total) return;
    int n = i / (RR * Kpad);
    int rem = i - n * (RR * Kpad);
    int r = rem / Kpad;
    int k = rem - r * Kpad;
    float v = (k < K0) ? W[((size_t)r * K0 + k) * 256 + n] : 0.f;
    WT[i] = f2bf(v);
}

// ---------------- dual-payload aggregation v5: 4-edge explicit staging ----------------
// r5's wave-uniform break serialized loads (1-2 in flight vs ~500cy LLC latency -> 2.7 TB/s).
// v5 issues all 4(+4 tail) independent row loads into NAMED registers before any FMA;
// clamped edges (f=0) re-load the previous row -> same address -> L1 hit, free.
// Accumulation order identical to v4 (f=0 terms add exact 0).
__global__ __launch_bounds__(256) void k_aggp(
        const unsigned short* __restrict__ xb,
        const int2* __restrict__ csrw, const int* __restrict__ offs,
        const float* __restrict__ nd, int nbase,
        unsigned short* __restrict__ Y2, unsigned short* __restrict__ Y3) {
    int lane = threadIdx.x & 63;
    int sub = threadIdx.x >> 6;
    int bn = blockIdx.x * 4 + sub;
    int n = nbase + bn;
    int r = blockIdx.y;
    int o0 = offs[r * (NN + 1) + n];
    int o1 = offs[r * (NN + 1) + n + 1];
    o0 = __builtin_amdgcn_readfirstlane(o0);
    o1 = __builtin_amdgcn_readfirstlane(o1);
    int cnt = o1 - o0;
    float ndv = nd[(size_t)r * NN + n];
    const int2* cs = csrw + (size_t)r * EE + o0;
    bool tl = lane < 6;          // tail cols 512..559
    float va[8], vc[8];
    #pragma unroll
    for (int q = 0; q < 8; q++) { va[q] = 0.f; vc[q] = 0.f; }

    for (int eb = 0; eb < cnt; eb += 64) {
        int rem = cnt - eb;                        // > 0
        int2 rec = cs[eb + min(lane, rem - 1)];    // coalesced record block
        int kmax = rem < 64 ? rem : 64;
        for (int kb = 0; kb < kmax; kb += 4) {
            int l1 = kb + 1 < kmax ? kb + 1 : kmax - 1;
            int l2 = kb + 2 < kmax ? kb + 2 : kmax - 1;
            int l3 = kb + 3 < kmax ? kb + 3 : kmax - 1;
            int s0 = __shfl(rec.x, kb, 64);
            int s1 = __shfl(rec.x, l1, 64);
            int s2 = __shfl(rec.x, l2, 64);
            int s3 = __shfl(rec.x, l3, 64);
            float f0 = __int_as_float(__shfl(rec.y, kb, 64));
            float f1 = kb + 1 < kmax ? __int_as_float(__shfl(rec.y, l1, 64)) : 0.f;
            float f2 = kb + 2 < kmax ? __int_as_float(__shfl(rec.y, l2, 64)) : 0.f;
            float f3 = kb + 3 < kmax ? __int_as_float(__shfl(rec.y, l3, 64)) : 0.f;
            const unsigned short* p0 = xb + (size_t)(unsigned)s0 * 560 + lane * 8;
            const unsigned short* p1 = xb + (size_t)(unsigned)s1 * 560 + lane * 8;
            const unsigned short* p2 = xb + (size_t)(unsigned)s2 * 560 + lane * 8;
            const unsigned short* p3 = xb + (size_t)(unsigned)s3 * 560 + lane * 8;
            short8 A0 = *(const short8*)p0;
            short8 A1 = *(const short8*)p1;
            short8 A2 = *(const short8*)p2;
            short8 A3 = *(const short8*)p3;
            short8 C0 = {}, C1 = {}, C2 = {}, C3 = {};
            if (tl) {
                C0 = *(const short8*)(p0 + 512);
                C1 = *(const short8*)(p1 + 512);
                C2 = *(const short8*)(p2 + 512);
                C3 = *(const short8*)(p3 + 512);
            }
            #pragma unroll
            for (int q = 0; q < 8; q++) {
                va[q] += f0 * bf2f((unsigned short)A0[q]);
                va[q] += f1 * bf2f((unsigned short)A1[q]);
                va[q] += f2 * bf2f((unsigned short)A2[q]);
                va[q] += f3 * bf2f((unsigned short)A3[q]);
            }
            if (tl) {
                #pragma unroll
                for (int q = 0; q < 8; q++) {
                    vc[q] += f0 * bf2f((unsigned short)C0[q]);
                    vc[q] += f1 * bf2f((unsigned short)C1[q]);
                    vc[q] += f2 * bf2f((unsigned short)C2[q]);
                    vc[q] += f3 * bf2f((unsigned short)C3[q]);
                }
            }
        }
    }
    short8 o;
    #pragma unroll
    for (int q = 0; q < 8; q++) o[q] = (short)f2bf(va[q] * ndv);
    if (lane < 32) {
        *(short8*)(Y2 + (size_t)bn * 2048 + r * 256 + lane * 8) = o;
    } else {
        *(short8*)(Y3 + (size_t)bn * 2432 + r * 304 + (lane - 32) * 8) = o;
    }
    if (tl) {
        short8 oc;
        #pragma unroll
        for (int q = 0; q < 8; q++) oc[q] = (short)f2bf(vc[q] * ndv);
        *(short8*)(Y3 + (size_t)bn * 2432 + r * 304 + 256 + lane * 8) = oc;
    }
}

// ---------------- generic bf16 MFMA GEMM (r0-proven), used for G projection ----------------
// flags: 1=addbias, 2=accum(read Cin fp32), 4=relu, 8=out bf16 (else fp32)
template<int TN>
__global__ __launch_bounds__(256) void k_gemm_bf(
        const unsigned short* __restrict__ A, int lda,
        const unsigned short* __restrict__ BT, int ldb,
        const float* __restrict__ bias,
        const float* __restrict__ Cin, int ldcin,
        void* __restrict__ Cout, int ldc,
        int M, int K, int flags) {
    constexpr int BN = TN * 32;
    __shared__ unsigned short As[128 * 64];
    __shared__ unsigned short Bs[BN * 64];
    int m0 = blockIdx.x * 128;
    int n0 = blockIdx.y * BN;
    int t = threadIdx.x;
    int w = t >> 6, l = t & 63;
    int qm = (w >> 1) * 64, qn = (w & 1) * (TN * 16);
    int lr = l & 15, lg = l >> 4;
    int lrow = l >> 3;
    int lch  = (l & 7) ^ lrow;

    floatx4 acc[4][TN];
    #pragma unroll
    for (int a = 0; a < 4; a++)
        #pragma unroll
        for (int b = 0; b < TN; b++)
            acc[a][b] = (floatx4){0.f, 0.f, 0.f, 0.f};

    for (int k0 = 0; k0 < K; k0 += 64) {
        #pragma unroll
        for (int j = 0; j < 4; j++) {
            int seg = w * 4 + j;
            int gr = m0 + seg * 8 + lrow; if (gr > M - 1) gr = M - 1;
            gload_lds16(A + (size_t)gr * lda + k0 + lch * 8, &As[seg * 512]);
        }
        #pragma unroll
        for (int j = 0; j < TN; j++) {
            int seg = w * TN + j;
            int row = n0 + seg * 8 + lrow;
            gload_lds16(BT + (size_t)row * ldb + k0 + lch * 8, &Bs[seg * 512]);
        }
        __syncthreads();
        #pragma unroll
        for (int ks = 0; ks < 2; ks++) {
            int slot = ((ks * 4 + lg) ^ (lr & 7)) * 8;
            short8 af[4], bf[TN];
            #pragma unroll
            for (int i = 0; i < 4; i++)
                af[i] = *(const short8*)&As[(qm + i * 16 + lr) * 64 + slot];
            #pragma unroll
            for (int i = 0; i < TN; i++)
                bf[i] = *(const short8*)&Bs[(qn + i * 16 + lr) * 64 + slot];
            #pragma unroll
            for (int tm = 0; tm < 4; tm++)
                #pragma unroll
                for (int tn = 0; tn < TN; tn++)
                    acc[tm][tn] = __builtin_amdgcn_mfma_f32_16x16x32_bf16(
                        af[tm], bf[tn], acc[tm][tn], 0, 0, 0);
        }
        __syncthreads();
    }

    int addbias = flags & 1, accum = flags & 2, relu = flags & 4, outbf = flags & 8;
    #pragma unroll
    for (int tm = 0; tm < 4; tm++) {
        int rbase = m0 + qm + tm * 16 + lg * 4;
        #pragma unroll
        for (int reg = 0; reg < 4; reg++) {
            int row = rbase + reg;
            if (row >= M) continue;
            #pragma unroll
            for (int tn = 0; tn < TN; tn++) {
                int col = n0 + qn + tn * 16 + lr;
                float v = acc[tm][tn][reg];
                if (addbias) v += bias[col];
                if (accum) v += Cin[(size_t)row * ldcin + col];
                if (relu) v = fmaxf(v, 0.f);
                if (outbf) ((unsigned short*)Cout)[(size_t)row * ldc + col] = f2bf(v);
                else       ((float*)Cout)[(size_t)row * ldc + col] = v;
            }
        }
    }
}

// ---------------- paired a-layer GEMM, BM=64/BN=64, XCD-swizzled sibling n-tiles -------------
// 1D grid 640. Decode: g=(x>>5)*8+(x&7) in [0,160) -> (z, m-block); nb=(x>>3)&3.
// The 4 n-siblings of a group get ids {base, base+8, base+16, base+24} == same id mod 8
// -> same XCD (round-robin dispatch) -> A-tile (256 KB) read once from LLC, 3x from L2.
__global__ __launch_bounds__(256) void k_gemm2(
        const unsigned short* __restrict__ Y2, const unsigned short* __restrict__ Y3,
        const unsigned short* __restrict__ WT2, const unsigned short* __restrict__ WT3,
        const float* __restrict__ bs, unsigned short* __restrict__ hb,
        int nbase, int M) {
    __shared__ unsigned short As[64 * 64];
    __shared__ unsigned short Bs[64 * 64];
    int x = blockIdx.x;
    int g = (x >> 5) * 8 + (x & 7);
    int nb = (x >> 3) & 3;
    if (g >= 158) return;          // 158 = 2 z * 79 m-blocks
    int z = g / 79;
    int mb = g - z * 79;
    const unsigned short* A  = z ? Y3 : Y2;
    const unsigned short* BT = z ? WT3 : WT2;
    int lda = z ? 2432 : 2048;
    int K = lda;
    const float* bias = bs + z * 512;
    int m0 = mb * 64;
    int n0 = nb * 64;
    int t = threadIdx.x;
    int w = t >> 6, l = t & 63;
    int qm = (w >> 1) * 32, qn = (w & 1) * 32;
    int lr = l & 15, lg = l >> 4;
    int lrow = l >> 3;
    int lch  = (l & 7) ^ lrow;

    floatx4 acc[2][2];
    #pragma unroll
    for (int a = 0; a < 2; a++)
        #pragma unroll
        for (int b = 0; b < 2; b++)
            acc[a][b] = (floatx4){0.f, 0.f, 0.f, 0.f};

    for (int k0 = 0; k0 < K; k0 += 64) {
        #pragma unroll
        for (int j = 0; j < 2; j++) {
            int seg = w * 2 + j;                   // 8 segs x 8 rows = 64 rows
            int gr = m0 + seg * 8 + lrow; if (gr > M - 1) gr = M - 1;
            gload_lds16(A + (size_t)gr * lda + k0 + lch * 8, &As[seg * 512]);
        }
        #pragma unroll
        for (int j = 0; j < 2; j++) {
            int seg = w * 2 + j;
            int row = n0 + seg * 8 + lrow;         // <= 255, WT has 256 rows
            gload_lds16(BT + (size_t)row * lda + k0 + lch * 8, &Bs[seg * 512]);
        }
        __syncthreads();
        #pragma unroll
        for (int ks = 0; ks < 2; ks++) {
            int slot = ((ks * 4 + lg) ^ (lr & 7)) * 8;
            short8 af[2], bf[2];
            #pragma unroll
            for (int i = 0; i < 2; i++)
                af[i] = *(const short8*)&As[(qm + i * 16 + lr) * 64 + slot];
            #pragma unroll
            for (int i = 0; i < 2; i++)
                bf[i] = *(const short8*)&Bs[(qn + i * 16 + lr) * 64 + slot];
            #pragma unroll
            for (int tm = 0; tm < 2; tm++)
                #pragma unroll
                for (int tn = 0; tn < 2; tn++)
                    acc[tm][tn] = __builtin_amdgcn_mfma_f32_16x16x32_bf16(
                        af[tm], bf[tn], acc[tm][tn], 0, 0, 0);
        }
        __syncthreads();
    }

    #pragma unroll
    for (int tm = 0; tm < 2; tm++) {
        int rbase = m0 + qm + tm * 16 + lg * 4;
        #pragma unroll
        for (int reg = 0; reg < 4; reg++) {
            int row = rbase + reg;
            if (row >= M) continue;
            #pragma unroll
            for (int tn = 0; tn < 2; tn++) {
                int col = n0 + qn + tn * 16 + lr;
                float v = fmaxf(acc[tm][tn][reg] + bias[col], 0.f);
                hb[(size_t)(nbase + row) * 512 + z * 256 + col] = f2bf(v);
            }
        }
    }
}

// ---------------- 16-dim projected aggregation v2: slot = relation pairs, rec-broadcast ------
__global__ __launch_bounds__(256) void k_aggAB(
        const int2* __restrict__ csrw, const int* __restrict__ offs,
        const float* __restrict__ nd, const float* __restrict__ G,
        const float* __restrict__ cfold, const float* __restrict__ cvec,
        float* __restrict__ AB) {
    int lane = threadIdx.x & 63, sub = threadIdx.x >> 6;
    int n = blockIdx.x * 4 + sub;
    int slot = lane >> 4, j = lane & 15;
    int jb = slot << 4;                     // group base lane for shfl
    float acc = 0.f;
    for (int hh = 0; hh < 2; hh++) {
        int r = slot + hh * 4;
        int o0 = offs[r * (NN + 1) + n];
        int o1 = offs[r * (NN + 1) + n + 1];
        float ndv = nd[(size_t)r * NN + n];
        const int2* cs = csrw + (size_t)r * EE + o0;
        int cnt = o1 - o0;
        float t0 = 0.f, t1 = 0.f;
        for (int eb = 0; eb < cnt; eb += 16) {
            int rem = cnt - eb;
            int2 rec = cs[eb + min(j, rem - 1)];   // 16 records per slot, coalesced
            int kmax = rem < 16 ? rem : 16;
            for (int k = 0; k < kmax; k += 2) {
                int s0 = __shfl(rec.x, jb + k, 64);
                float f0 = __int_as_float(__shfl(rec.y, jb + k, 64));
                int k1 = k + 1 < kmax ? k + 1 : kmax - 1;
                int s1 = __shfl(rec.x, jb + k1, 64);
                float f1 = (k + 1 < kmax) ? __int_as_float(__shfl(rec.y, jb + k1, 64)) : 0.f;
                t0 += f0 * G[(size_t)(unsigned)s0 * 128 + r * 16 + j];
                t1 += f1 * G[(size_t)(unsigned)s1 * 128 + r * 16 + j];
            }
        }
        acc += ndv * (t0 + t1);
    }
    acc += __shfl_xor(acc, 16, 64);
    acc += __shfl_xor(acc, 32, 64);
    if (lane < 16) AB[(size_t)n * 16 + j] = acc + cfold[j] + (j < 8 ? cvec[j] : 0.f);
}

// ---------------- per-edge decoder (float4, cvec pre-folded) ----------------
__global__ void k_dec(const int* __restrict__ dsrc, const int* __restrict__ ddst,
                      const float* __restrict__ AB, float* __restrict__ out) {
    int e = blockIdx.x * 256 + threadIdx.x;
    if (e >= EDD) return;
    int s = dsrc[e], d = ddst[e];
    const float4* as = (const float4*)(AB + (size_t)s * 16);
    const float4* ad = (const float4*)(AB + (size_t)d * 16 + 8);
    float4 x0 = as[0], x1 = as[1], y0 = ad[0], y1 = ad[1];
    float4 o0 = {x0.x + y0.x, x0.y + y0.y, x0.z + y0.z, x0.w + y0.w};
    float4 o1 = {x1.x + y1.x, x1.y + y1.y, x1.z + y1.z, x1.w + y1.w};
    float4* op = (float4*)(out + (size_t)e * 8);
    op[0] = o0; op[1] = o1;
}

extern "C" void kernel_launch(void* const* d_in, const int* in_sizes, int n_in,
                              void* d_out, int out_size, void* d_ws, size_t ws_size,
                              hipStream_t stream) {
    const float* x2  = (const float*)d_in[0];
    const float* x3  = (const float*)d_in[1];
    const int*   src = (const int*)d_in[2];
    const int*   dst = (const int*)d_in[3];
    const int*   dsrc = (const int*)d_in[4];
    const int*   ddst = (const int*)d_in[5];
    const float* W2a = (const float*)d_in[6];
    const float* b2a = (const float*)d_in[7];
    const float* W2b = (const float*)d_in[8];
    const float* b2b = (const float*)d_in[9];
    const float* W3a = (const float*)d_in[10];
    const float* b3a = (const float*)d_in[11];
    const float* W3b = (const float*)d_in[12];
    const float* b3b = (const float*)d_in[13];
    const float* Wp1 = (const float*)d_in[14];
    const float* bp1 = (const float*)d_in[15];
    const float* Wp2 = (const float*)d_in[16];
    const float* bp2 = (const float*)d_in[17];
    float* out = (float*)d_out;

    // ---- workspace layout (~172 MB < proven 182.4 MB bound) ----
    char* ws = (char*)d_ws;
    size_t off = 0;
    auto alloc = [&](size_t nbytes) {
        char* p = ws + off;
        off += nbytes;
        off = (off + 255) & ~(size_t)255;
        return p;
    };
    float* ns   = (float*)alloc((size_t)RR * NN * 4);        // aliases outdeg
    float* nd   = (float*)alloc((size_t)RR * NN * 4);        // aliases indeg
    int*   offs = (int*)alloc((size_t)RR * (NN + 1) * 4);
    int2*  csrw = (int2*)alloc((size_t)RR * EE * 8);
    unsigned short* XH     = (unsigned short*)alloc((size_t)NN * 560 * 2);  // [x2|x3|pad] interleaved
    unsigned short* hbuf23 = (unsigned short*)alloc((size_t)NN * 512 * 2);  // [h2a|h3a] interleaved
    unsigned short* WT2a   = (unsigned short*)alloc((size_t)256 * 2048 * 2);
    unsigned short* WT3a   = (unsigned short*)alloc((size_t)256 * 2432 * 2);
    unsigned short* FmatT  = (unsigned short*)alloc((size_t)128 * 512 * 2);
    char* YR = alloc((size_t)CH * (2048 + 2432) * 2);        // Y2a|Y3a; also cursor/htmp/G/AB
    float* Mcat  = (float*)alloc(4096 * 4);
    float* cvec  = (float*)alloc(64 * 4);
    float* bsums = (float*)alloc(1024 * 4);
    float* cfold = (float*)alloc(64 * 4);
    int*   bsum  = (int*)alloc((size_t)RR * SCB * 4);

    unsigned short* Y2a = (unsigned short*)YR;
    unsigned short* Y3a = Y2a + (size_t)CH * 2048;
    int*   outdeg = (int*)ns;
    int*   indeg  = (int*)nd;
    int*   cursor = (int*)YR;                               // 1.6 MB, live only until k_fillw3
    unsigned char* htmp = (unsigned char*)(YR + (4 << 20)); // 12.8 MB, live during histp/reduce
    float* G      = (float*)YR;                             // [NN x 128] f32, live after phase a
    float* AB     = (float*)(YR + (size_t)NN * 128 * 4);    // 3.2 MB after G

    // ---- graph prep ----
    hipMemsetAsync(cursor, 0, (size_t)RR * NN * 4, stream);

    k_histp<<<dim3(CHK, RR, 2), 256, 0, stream>>>(src, dst, htmp);
    k_reduce<<<(2 * RR * 12512 + 255) / 256, 256, 0, stream>>>(htmp, outdeg, indeg);
    k_scanA<<<dim3(SCB, RR), 256, 0, stream>>>(indeg, bsum);
    k_scanB<<<RR, 256, 0, stream>>>(bsum, offs);
    k_scanC<<<dim3(SCB, RR), 256, 0, stream>>>(indeg, bsum, offs);
    k_norms<<<(RR * NN + 255) / 256, 256, 0, stream>>>(outdeg, indeg);
    k_fillw3<<<dim3(8, RR, 8), 256, 0, stream>>>(src, dst, offs, ns, cursor, csrw);
    k_prep<<<18, 256, 0, stream>>>(Wp1, Wp2, bp1, bp2, b2a, b2b, b3a, b3b, Mcat, cvec, bsums);
    k_fold<<<257, 256, 0, stream>>>(W2b, W3b, Mcat, bsums, FmatT, cfold);

    k_castx<<<(NN * 70 + 255) / 256, 256, 0, stream>>>(x2, x3, XH);
    k_wt2<<<dim3((256 * RR * 304 + 255) / 256, 2), 256, 0, stream>>>(W2a, W3a, WT2a, WT3a);

    // ---- phase a: chunked dual aggregation + paired GEMM -> hbuf23 (relu bf16) ----
    for (int c = 0; c < NN / CH; c++) {
        k_aggp<<<dim3(CH / 4, RR), 256, 0, stream>>>(XH, csrw, offs, nd, c * CH, Y2a, Y3a);
        k_gemm2<<<640, 256, 0, stream>>>(
            Y2a, Y3a, WT2a, WT3a, bsums, hbuf23, c * CH, CH);
    }

    // ---- phase b (folded): G = hbuf23 @ FmatT^T  [NN x 128] f32 ----
    k_gemm_bf<1><<<dim3((NN + 127) / 128, 4), 256, 0, stream>>>(
        hbuf23, 512, FmatT, 512, bsums, (const float*)nullptr, 0,
        (void*)G, 128, NN, 512, 0);

    // ---- projected aggregation -> AB, then decoder ----
    k_aggAB<<<NN / 4, 256, 0, stream>>>(csrw, offs, nd, G, cfold, cvec, AB);
    k_dec<<<(EDD + 255) / 256, 256, 0, stream>>>(dsrc, ddst, AB, out);
}